// Round 19
// baseline (428.461 us; speedup 1.0000x reference)
//
#include <hip/hip_runtime.h>
#include <hip/hip_bf16.h>

typedef unsigned short u16;
typedef __attribute__((ext_vector_type(8))) short short8;
typedef __attribute__((ext_vector_type(8))) unsigned short ushort8;
typedef __attribute__((ext_vector_type(4))) float f32x4;

#define BB 2
#define NN 256
#define DD 128
#define TDD 64
#define LL 4
#define NGROUP 32
#define NROWS (BB*NN*NN)      // 131072 edge rows
#define LDS_STR 68            // padded LDS stride for fp32 embed kernels

#define LOG1E4 9.210340371976184f
#define TWO_PI 6.283185307179586f

// ---------------- fp32 tile GEMM (node embed kernel only) ----------------
#define TILE_GEMM(AT, WPTR, ACC) do {                                          \
  _Pragma("unroll 4")                                                          \
  for (int k = 0; k < 128; ++k) {                                              \
    const float4 w4 = *reinterpret_cast<const float4*>((WPTR) + k*128 + tx*4); \
    const float4 a0 = *reinterpret_cast<const float4*>(&(AT)[k*LDS_STR + ty*8]);     \
    const float4 a1 = *reinterpret_cast<const float4*>(&(AT)[k*LDS_STR + ty*8 + 4]); \
    const float av[8] = {a0.x,a0.y,a0.z,a0.w,a1.x,a1.y,a1.z,a1.w};             \
    const float wv[4] = {w4.x,w4.y,w4.z,w4.w};                                 \
    _Pragma("unroll") for (int r = 0; r < 8; ++r)                              \
      _Pragma("unroll") for (int c = 0; c < 4; ++c)                            \
        ACC[r][c] += av[r]*wv[c];                                              \
  }                                                                            \
} while (0)

__device__ __forceinline__ float sigmoidf_(float x) {
  return 1.f / (1.f + __expf(-x));
}

// round-to-nearest-even f32 -> bf16 bits (proven r3-r17)
__device__ __forceinline__ u16 f2bf(float f) {
  union { float f; unsigned int u; } c; c.f = f;
  unsigned int r = (c.u + 0x7FFFu + ((c.u >> 16) & 1u)) >> 16;
  return (u16)r;
}

// ---- time embedding pipeline -> tproj[L][B][D] (parallel over b, unrolled) ----
__global__ __launch_bounds__(512) void k_time(
    const float* __restrict__ t,
    const float* __restrict__ te1_W, const float* __restrict__ te1_b,
    const float* __restrict__ te2_W, const float* __restrict__ te2_b,
    const float* __restrict__ tl_W,  const float* __restrict__ tl_b,
    float* __restrict__ tproj) {
  __shared__ float temb[BB][128], h1[BB][64], rt[BB][64];
  const int tid = threadIdx.x;
  const int b  = tid >> 8;           // 0..1
  const int t2 = tid & 255;          // 0..255 within batch group
  const float tv = t[b];
  if (t2 < 128) {
    int j = t2 & 63;
    float f = expf(-LOG1E4 * (float)j / 64.f);
    float a = tv * f;
    temb[b][t2] = (t2 < 64) ? cosf(a) : sinf(a);
  }
  __syncthreads();
  if (t2 < 64) {
    float acc = te1_b[t2];
#pragma unroll
    for (int k = 0; k < 128; ++k) acc += temb[b][k] * te1_W[k*64 + t2];
    h1[b][t2] = fmaxf(acc, 0.f);
  }
  __syncthreads();
  if (t2 < 64) {
    float acc = te2_b[t2];
#pragma unroll
    for (int k = 0; k < 64; ++k) acc += h1[b][k] * te2_W[k*64 + t2];
    rt[b][t2] = fmaxf(acc, 0.f);     // relu(te)
  }
  __syncthreads();
  if (t2 < 128) {
#pragma unroll
    for (int i = 0; i < LL; ++i) {
      float acc = tl_b[i*128 + t2];
#pragma unroll
      for (int k = 0; k < 64; ++k) acc += rt[b][k] * tl_W[(i*64 + k)*128 + t2];
      tproj[(i*BB + b)*128 + t2] = acc;
    }
  }
}

// ---------------- node pos-embed + node_W GEMM -> x (512 x 128) ----------------
// Fast trig: args bounded by 2*pi (coords in [0,1]); error << bf16 rounding.
__global__ __launch_bounds__(256) void k_node_embed(
    const float* __restrict__ coords, const float* __restrict__ W,
    const float* __restrict__ bias, float* __restrict__ x_out) {
  __shared__ float at[128*LDS_STR];
  int tid = threadIdx.x;
  int row = tid >> 2, part = tid & 3;
  int R = blockIdx.x*64 + row;
  float cy = coords[R*2 + 0], cx = coords[R*2 + 1];
#pragma unroll
  for (int q = 0; q < 32; ++q) {
    int c = part*32 + q;
    int k = (c < 64) ? c : c - 64;
    float v = (c < 64) ? cy : cx;
    int m = k >> 1;
    float inv = __expf(-LOG1E4 * (float)m / 32.f);
    float a = v * TWO_PI * inv;
    at[c*LDS_STR + row] = (k & 1) ? __cosf(a) : __sinf(a);
  }
  __syncthreads();
  int tx = tid & 31, ty = tid >> 5;
  float acc[8][4] = {};
  TILE_GEMM(at, W, acc);
  float4 bb4 = *reinterpret_cast<const float4*>(bias + tx*4);
#pragma unroll
  for (int r = 0; r < 8; ++r) {
    int R2 = blockIdx.x*64 + ty*8 + r;
    float4 o = {acc[r][0]+bb4.x, acc[r][1]+bb4.y, acc[r][2]+bb4.z, acc[r][3]+bb4.w};
    *reinterpret_cast<float4*>(x_out + (size_t)R2*128 + tx*4) = o;
  }
}

// ------- edge_W^T bf16 prep for MFMA edge embed: WTE[n][k] -------
__global__ __launch_bounds__(256) void k_wprep_e(
    const float* __restrict__ EW, u16* __restrict__ WTE) {
  int idx = blockIdx.x*256 + threadIdx.x;    // 0..16383
  int n = idx >> 7, k = idx & 127;
  WTE[n*128 + k] = f2bf(EW[(size_t)k*128 + n]);
}

// ------- MFMA edge pos-embed: e = posembed(adj) @ edge_W + edge_b -------
// Fast trig: |a| = |adj|*inv <= ~5 (randn input); error << bf16 rounding.
__global__ __launch_bounds__(256, 3) void k_edge_embed2(
    const float* __restrict__ adj, const u16* __restrict__ WTE,
    const float* __restrict__ bias, float* __restrict__ e_out) {
  __shared__ __align__(16) u16 Abuf[64*128];    // 16 KB pos-embed bf16
  __shared__ __align__(16) u16 Wbuf[128*128];   // 32 KB edge_W^T

  const int tid = threadIdx.x;
  const int blk = blockIdx.x;
  const int w  = tid >> 6;
  const int l  = tid & 63;
  const int lg = l >> 4;
  const int ln = l & 15;

  // ---- stage WTE -> Wbuf (chunk ^ (n&7) swizzle), 2 threads per row ----
  {
    const int r = tid >> 1, h = tid & 1;
    const int r7 = r & 7;
    const u16* src = WTE + r*128;
    u16* dst = Wbuf + r*128;
#pragma unroll
    for (int q = 0; q < 8; ++q) {
      int c = h*8 + q;
      short8 v = *reinterpret_cast<const short8*>(src + c*8);
      *reinterpret_cast<short8*>(dst + ((c ^ r7) << 3)) = v;
    }
  }
  // ---- compute pos-embed row strip -> bf16 Abuf (chunk ^ (row&7) swizzle) ----
  {
    const int r = tid >> 2;          // 0..63
    const int p = tid & 3;
    const float v = adj[(size_t)blk*64 + r];
    const int r7 = r & 7;
    u16* arow = Abuf + r*128;
#pragma unroll
    for (int q = 0; q < 4; ++q) {
      u16 h8[8];
#pragma unroll
      for (int j = 0; j < 8; ++j) {
        int k = (p*4 + q)*8 + j;     // column 0..127
        int m = k >> 1;
        float inv = __expf(-LOG1E4 * (float)m / 64.f);
        float a = v * inv;
        h8[j] = f2bf((k & 1) ? __cosf(a) : __sinf(a));
      }
      int pc = (p*4 + q) ^ r7;
      *reinterpret_cast<ushort8*>(arow + pc*8) = *reinterpret_cast<ushort8*>(h8);
    }
  }
  __syncthreads();

  // ---- MFMA: acc = bias; acc += posembed @ edge_W ----
  f32x4 acc[8];
#pragma unroll
  for (int nt = 0; nt < 8; ++nt) {
    const float bv = bias[nt*16 + ln];
#pragma unroll
    for (int rg = 0; rg < 4; ++rg) acc[nt][rg] = bv;
  }
  {
    const u16* arow = Abuf + (w*16 + ln)*128;
    const int r7 = ln & 7;
    __builtin_amdgcn_s_setprio(1);   // T5: favor MFMA-phase waves
#pragma unroll
    for (int ks = 0; ks < 4; ++ks) {
      short8 a = *reinterpret_cast<const short8*>(arow + (((ks*4 + lg) ^ r7) << 3));
#pragma unroll
      for (int nt = 0; nt < 8; ++nt) {
        short8 bw = *reinterpret_cast<const short8*>(
            Wbuf + (nt*16 + ln)*128 + (((ks*4 + lg) ^ (ln & 7)) << 3));
        acc[nt] = __builtin_amdgcn_mfma_f32_16x16x32_bf16(a, bw, acc[nt], 0, 0, 0);
      }
    }
    __builtin_amdgcn_s_setprio(0);
  }
#pragma unroll
  for (int nt = 0; nt < 8; ++nt)
#pragma unroll
    for (int rg = 0; rg < 4; ++rg)
      e_out[((size_t)blk*64 + w*16 + lg*4 + rg)*128 + nt*16 + ln] = acc[nt][rg];
}

// ---------------- per-layer node linears: Uh,Vh,Ax,Bx (512 rows) ----------------
__global__ __launch_bounds__(128) void k_node4(
    const float* __restrict__ x,
    const float* __restrict__ UW, const float* __restrict__ Ub,
    const float* __restrict__ VW, const float* __restrict__ Vb,
    const float* __restrict__ AW, const float* __restrict__ Ab,
    const float* __restrict__ BW, const float* __restrict__ Bb,
    float* __restrict__ Uh, float* __restrict__ Vh,
    float* __restrict__ Axo, float* __restrict__ Bxo) {
  __shared__ float xr[128];
  int R = blockIdx.x, d = threadIdx.x;
  xr[d] = x[(size_t)R*128 + d];
  __syncthreads();
  float au = Ub[d], av = Vb[d], aa = Ab[d], ab = Bb[d];
  for (int k = 0; k < 128; ++k) {
    float xv = xr[k];
    au += xv * UW[k*128 + d];
    av += xv * VW[k*128 + d];
    aa += xv * AW[k*128 + d];
    ab += xv * BW[k*128 + d];
  }
  Uh[(size_t)R*128 + d] = au;
  Vh[(size_t)R*128 + d] = av;
  Axo[(size_t)R*128 + d] = aa;
  Bxo[(size_t)R*128 + d] = ab;
}

// ---------------- weight prep: bf16 transposed copies WT[n][k] ----------------
__global__ __launch_bounds__(256) void k_wprep(
    const float* __restrict__ CW, const float* __restrict__ PW,
    u16* __restrict__ WTC, u16* __restrict__ WTP) {
  int idx = blockIdx.x*256 + threadIdx.x;    // 0..131071
  int m = idx >> 14;                          // 0..7 (layer*2 + type)
  int r = idx & 16383;
  int layer = m >> 1;
  int n = r >> 7, k = r & 127;
  if ((m & 1) == 0)
    WTC[layer*16384 + n*128 + k] = f2bf(CW[(size_t)layer*16384 + k*128 + n]);
  else
    WTP[layer*16384 + n*128 + k] = f2bf(PW[(size_t)layer*16384 + k*128 + n]);
}

// ===== fused per-layer MFMA kernel: 512-thr / 128-row blocks (r17 + T5) =====
__global__ __launch_bounds__(512, 2) void k_layer(
    float* __restrict__ e,
    const u16* __restrict__ WTC, const u16* __restrict__ WTP,
    const float* __restrict__ Cb, const float* __restrict__ Ax,
    const float* __restrict__ Bx, const float* __restrict__ Vh,
    const float* __restrict__ lnes_g, const float* __restrict__ lneb_g,
    const float* __restrict__ tp_g,
    const float* __restrict__ plos_g, const float* __restrict__ plobl_g,
    const float* __restrict__ plob_g,
    float* __restrict__ aggP) {

  __shared__ __align__(16) u16 Abuf[128*128];   // 32 KB (e, then sv)
  __shared__ __align__(16) u16 Wbuf[128*128];   // 32 KB (WTC, then WTP)

  const int tid = threadIdx.x;
  const int blk0 = blockIdx.x;
  const int blk = ((blk0 & 7) << 7) | (blk0 >> 3);   // XCD swizzle (1024%8==0)
  const int bi  = blk >> 1;          // b*256 + i
  const int b   = bi >> 8;
  const int jh  = blk & 1;           // 128-row half
  const size_t rbase = (size_t)bi*256 + jh*128;

  const int w  = tid >> 6;           // 0..7
  const int l  = tid & 63;
  const int lg = l >> 4;             // 0..3
  const int ln = l & 15;             // 0..15

  // ---- stage e tile -> bf16 Abuf (chunk ^ (row&7) swizzle) ----
  {
    const int r = tid >> 2;          // 0..127
    const int p = tid & 3;
    const float* src = e + (rbase + r)*128 + p*32;
    const int r7 = r & 7;
    u16* arow = Abuf + r*128;
#pragma unroll
    for (int q = 0; q < 4; ++q) {
      float4 f0 = *reinterpret_cast<const float4*>(src + q*8);
      float4 f1 = *reinterpret_cast<const float4*>(src + q*8 + 4);
      int pc = (p*4 + q) ^ r7;
      ushort8 h = {f2bf(f0.x),f2bf(f0.y),f2bf(f0.z),f2bf(f0.w),
                   f2bf(f1.x),f2bf(f1.y),f2bf(f1.z),f2bf(f1.w)};
      *reinterpret_cast<ushort8*>(arow + pc*8) = h;
    }
  }
  // ---- stage WTC -> Wbuf (swizzled), 4 threads per row ----
  {
    const int r = tid >> 2;          // 0..127
    const int h = tid & 3;
    const int r7 = r & 7;
    const u16* src = WTC + r*128;
    u16* dst = Wbuf + r*128;
#pragma unroll
    for (int q = 0; q < 4; ++q) {
      int c = h*4 + q;               // 16B chunk index 0..15
      short8 v = *reinterpret_cast<const short8*>(src + c*8);
      *reinterpret_cast<short8*>(dst + ((c ^ r7) << 3)) = v;
    }
  }
  __syncthreads();   // barrier 1: Wbuf + Abuf visible

  const int lrow0 = w*16 + lg*4;           // lane's first row, tile-local
  const int jrow0 = jh*128 + lrow0;        // same, node-local

  // ---- gate init: Cb + Ax[i] + Bx[j] ----
  f32x4 acc[8];
#pragma unroll
  for (int nt = 0; nt < 8; ++nt) {
    const int c = nt*16 + ln;
    const float cbax = Cb[c] + Ax[(size_t)bi*128 + c];
#pragma unroll
    for (int rg = 0; rg < 4; ++rg)
      acc[nt][rg] = cbax + Bx[((size_t)b*256 + jrow0 + rg)*128 + c];
  }

  // ---- GEMM1: += e @ C_W (A and B both from LDS) ----
  {
    const u16* arow = Abuf + (w*16 + ln)*128;
    const int r7 = ln & 7;
    __builtin_amdgcn_s_setprio(1);   // T5: favor MFMA-phase waves
#pragma unroll
    for (int ks = 0; ks < 4; ++ks) {
      short8 a = *reinterpret_cast<const short8*>(arow + (((ks*4 + lg) ^ r7) << 3));
#pragma unroll
      for (int nt = 0; nt < 8; ++nt) {
        short8 bw = *reinterpret_cast<const short8*>(
            Wbuf + (nt*16 + ln)*128 + (((ks*4 + lg) ^ (ln & 7)) << 3));
        acc[nt] = __builtin_amdgcn_mfma_f32_16x16x32_bf16(a, bw, acc[nt], 0, 0, 0);
      }
    }
    __builtin_amdgcn_s_setprio(0);
  }

  // ---- per-row pipeline: agg, LN1+relu+tproj, LN2+silu -> sv to Abuf ----
  float av[8] = {0.f,0.f,0.f,0.f,0.f,0.f,0.f,0.f};
  float tp_[8], ls_[8], lb_[8], ps_[8], pl_[8];
#pragma unroll
  for (int nt = 0; nt < 8; ++nt) {
    const int c = nt*16 + ln;
    tp_[nt] = tp_g[b*128 + c];
    ls_[nt] = lnes_g[c];  lb_[nt] = lneb_g[c];
    ps_[nt] = plos_g[c];  pl_[nt] = plobl_g[c];
  }

#pragma unroll
  for (int rg = 0; rg < 4; ++rg) {
    float ss = 0.f, s2 = 0.f;
#pragma unroll
    for (int nt = 0; nt < 8; ++nt) { float g = acc[nt][rg]; ss += g; s2 += g*g; }
    ss += __shfl_xor(ss, 1);  s2 += __shfl_xor(s2, 1);
    ss += __shfl_xor(ss, 2);  s2 += __shfl_xor(s2, 2);
    ss += __shfl_xor(ss, 4);  s2 += __shfl_xor(s2, 4);
    ss += __shfl_xor(ss, 8);  s2 += __shfl_xor(s2, 8);
    const float mean = ss * (1.f/128.f);
    const float rs = rsqrtf(s2 * (1.f/128.f) - mean*mean + 1e-5f);
    const size_t vrow = ((size_t)b*256 + jrow0 + rg)*128;
    float s3 = 0.f, s4 = 0.f;
#pragma unroll
    for (int nt = 0; nt < 8; ++nt) {
      const float g = acc[nt][rg];
      av[nt] += Vh[vrow + nt*16 + ln] * sigmoidf_(g);
      float tv = fmaxf((g - mean)*rs*ls_[nt] + lb_[nt], 0.f) + tp_[nt];
      acc[nt][rg] = tv;
      s3 += tv;  s4 += tv*tv;
    }
    s3 += __shfl_xor(s3, 1);  s4 += __shfl_xor(s4, 1);
    s3 += __shfl_xor(s3, 2);  s4 += __shfl_xor(s4, 2);
    s3 += __shfl_xor(s3, 4);  s4 += __shfl_xor(s4, 4);
    s3 += __shfl_xor(s3, 8);  s4 += __shfl_xor(s4, 8);
    const float mean2 = s3 * (1.f/128.f);
    const float rs2 = rsqrtf(s4 * (1.f/128.f) - mean2*mean2 + 1e-5f);
    const int rr = lrow0 + rg;
    const int rr7 = rr & 7;
#pragma unroll
    for (int nt = 0; nt < 8; ++nt) {
      float vv = (acc[nt][rg] - mean2)*rs2*ps_[nt] + pl_[nt];
      vv = vv * sigmoidf_(vv);
      const int cc = nt*16 + ln;
      const int pc = (cc >> 3) ^ rr7;
      Abuf[rr*128 + pc*8 + (cc & 7)] = f2bf(vv);
    }
  }

  // ---- all waves done with Wbuf(WTC); restage WTP ----
  __syncthreads();
  {
    const int r = tid >> 2;
    const int h = tid & 3;
    const int r7 = r & 7;
    const u16* src = WTP + r*128;
    u16* dst = Wbuf + r*128;
#pragma unroll
    for (int q = 0; q < 4; ++q) {
      int c = h*4 + q;
      short8 v = *reinterpret_cast<const short8*>(src + c*8);
      *reinterpret_cast<short8*>(dst + ((c ^ r7) << 3)) = v;
    }
  }
  __syncthreads();

  // ---- GEMM2: acc2 = sv @ plo_W ----
  f32x4 acc2[8];
#pragma unroll
  for (int nt = 0; nt < 8; ++nt) acc2[nt] = (f32x4)(0.f);
  {
    const u16* arow = Abuf + (w*16 + ln)*128;
    const int r7 = ln & 7;
    __builtin_amdgcn_s_setprio(1);   // T5
#pragma unroll
    for (int ks = 0; ks < 4; ++ks) {
      short8 a = *reinterpret_cast<const short8*>(arow + (((ks*4 + lg) ^ r7) << 3));
#pragma unroll
      for (int nt = 0; nt < 8; ++nt) {
        short8 bw = *reinterpret_cast<const short8*>(
            Wbuf + (nt*16 + ln)*128 + (((ks*4 + lg) ^ (ln & 7)) << 3));
        acc2[nt] = __builtin_amdgcn_mfma_f32_16x16x32_bf16(a, bw, acc2[nt], 0, 0, 0);
      }
    }
    __builtin_amdgcn_s_setprio(0);
  }

  // ---- e += acc2 + plo_b  (RMW; residual read L2/L3-hot) ----
#pragma unroll
  for (int nt = 0; nt < 8; ++nt) {
    const float pbv = plob_g[nt*16 + ln];
#pragma unroll
    for (int rg = 0; rg < 4; ++rg) {
      float* ep = e + (rbase + lrow0 + rg)*128 + nt*16 + ln;
      *ep = *ep + acc2[nt][rg] + pbv;
    }
  }

  // ---- agg: reduce lane partials over wave's 16 rows ----
#pragma unroll
  for (int nt = 0; nt < 8; ++nt) {
    float v = av[nt];
    v += __shfl_xor(v, 16);
    v += __shfl_xor(v, 32);
    av[nt] = v;
  }
  if (lg == 0) {
#pragma unroll
    for (int nt = 0; nt < 8; ++nt)
      aggP[((size_t)blk*8 + w)*128 + nt*16 + ln] = av[nt];
  }
}

// ---------------- x update: x += relu(LN(Uh + agg)) ----------------
__global__ __launch_bounds__(128) void k_xupd(
    const float* __restrict__ aggP, const float* __restrict__ Uh,
    const float* __restrict__ lnh_s, const float* __restrict__ lnh_b,
    float* __restrict__ x) {
  int bi = blockIdx.x, d = threadIdx.x;
  float u = Uh[(size_t)bi*128 + d];
#pragma unroll
  for (int st = 0; st < 16; ++st) u += aggP[((size_t)bi*16 + st)*128 + d];
  float s = u, s2 = u*u;
#pragma unroll
  for (int m = 1; m <= 32; m <<= 1) { s += __shfl_xor(s, m); s2 += __shfl_xor(s2, m); }
  __shared__ float red[4];
  int wid = d >> 6;
  if ((d & 63) == 0) { red[wid] = s; red[2 + wid] = s2; }
  __syncthreads();
  s = red[0] + red[1];  s2 = red[2] + red[3];
  float mean = s * (1.f/128.f);
  float rs = rsqrtf(s2 * (1.f/128.f) - mean*mean + 1e-5f);
  x[(size_t)bi*128 + d] += fmaxf((u - mean)*rs*lnh_s[d] + lnh_b[d], 0.f);
}

// ---------------- zero the GN stats accumulators ----------------
__global__ __launch_bounds__(128) void k_zero(float* __restrict__ p) {
  p[threadIdx.x] = 0.f;
}

// ---------- GN stats, group-aligned: one float4 = one group ----------
__global__ __launch_bounds__(256) void k_gnstats2(
    const float* __restrict__ e, float* __restrict__ sraw) {
  const int blk = blockIdx.x;      // 512 blocks x 256 rows
  const int b = blk >> 8;
  const int c = threadIdx.x & 31;  // group == float4 chunk
  const int r0 = threadIdx.x >> 5; // 0..7
  float s = 0.f, s2 = 0.f;
  for (int it = 0; it < 32; ++it) {
    size_t row = (size_t)blk*256 + it*8 + r0;
    float4 f = *reinterpret_cast<const float4*>(e + row*128 + c*4);
    s  += f.x + f.y + f.z + f.w;
    s2 += f.x*f.x + f.y*f.y + f.z*f.z + f.w*f.w;
  }
  __shared__ float red[256], red2[256];
  red[threadIdx.x] = s;  red2[threadIdx.x] = s2;
  __syncthreads();
  if (threadIdx.x < 32) {
    float S = 0.f, S2 = 0.f;
#pragma unroll
    for (int k = 0; k < 8; ++k) { S += red[k*32 + threadIdx.x]; S2 += red2[k*32 + threadIdx.x]; }
    atomicAdd(&sraw[((size_t)b*32 + threadIdx.x)*2],     S);
    atomicAdd(&sraw[((size_t)b*32 + threadIdx.x)*2 + 1], S2);
  }
}

// ---------------- finalize GN stats ----------------
__global__ __launch_bounds__(64) void k_gnfin(
    const float* __restrict__ raw, float* __restrict__ stats) {
  int i = threadIdx.x;
  const float cnt = (float)(NN*NN*4);
  float S  = raw[i*2];
  float S2 = raw[i*2 + 1];
  float mean = S / cnt;
  float var = S2 / cnt - mean*mean;
  stats[i*2]     = mean;
  stats[i*2 + 1] = rsqrtf(var + 1e-5f);
}

// ---------------- final: out = relu(gn(e)) . conv_W + conv_b ----------------
__global__ __launch_bounds__(256) void k_out(
    const float* __restrict__ e, const float* __restrict__ stats,
    const float* __restrict__ gn_s, const float* __restrict__ gn_b,
    const float* __restrict__ convW, const float* __restrict__ convb,
    float* __restrict__ out) {
  int tid = threadIdx.x;
  int row = tid >> 2, part = tid & 3;
  size_t R = (size_t)blockIdx.x*64 + row;
  size_t b = R >> 16;
  float acc = 0.f;
  const float4* er = reinterpret_cast<const float4*>(e + R*128 + part*32);
#pragma unroll
  for (int q = 0; q < 8; ++q) {
    float4 f = er[q];
    float fv[4] = {f.x, f.y, f.z, f.w};
#pragma unroll
    for (int lidx = 0; lidx < 4; ++lidx) {
      int c = part*32 + q*4 + lidx;
      int g = c >> 2;
      float mean = stats[(b*NGROUP + g)*2 + 0];
      float rs   = stats[(b*NGROUP + g)*2 + 1];
      float t = (fv[lidx] - mean)*rs*gn_s[c] + gn_b[c];
      acc += fmaxf(t, 0.f) * convW[c];
    }
  }
  acc += __shfl_xor(acc, 1);
  acc += __shfl_xor(acc, 2);
  if (part == 0) out[R] = acc + convb[0];
}

extern "C" void kernel_launch(void* const* d_in, const int* in_sizes, int n_in,
                              void* d_out, int out_size, void* d_ws, size_t ws_size,
                              hipStream_t stream) {
  const float* coords  = (const float*)d_in[0];
  const float* adj_t   = (const float*)d_in[1];
  const float* t       = (const float*)d_in[2];
  const float* node_W  = (const float*)d_in[3];
  const float* node_b  = (const float*)d_in[4];
  const float* edge_W  = (const float*)d_in[5];
  const float* edge_b  = (const float*)d_in[6];
  const float* te1_W   = (const float*)d_in[7];
  const float* te1_b   = (const float*)d_in[8];
  const float* te2_W   = (const float*)d_in[9];
  const float* te2_b   = (const float*)d_in[10];
  const float* A_W     = (const float*)d_in[11];
  const float* A_b     = (const float*)d_in[12];
  const float* B_W     = (const float*)d_in[13];
  const float* B_b     = (const float*)d_in[14];
  const float* C_W     = (const float*)d_in[15];
  const float* C_b     = (const float*)d_in[16];
  const float* U_W     = (const float*)d_in[17];
  const float* U_b     = (const float*)d_in[18];
  const float* V_W     = (const float*)d_in[19];
  const float* V_b     = (const float*)d_in[20];
  const float* lnh_s   = (const float*)d_in[21];
  const float* lnh_b   = (const float*)d_in[22];
  const float* lne_s   = (const float*)d_in[23];
  const float* lne_b   = (const float*)d_in[24];
  const float* tl_W    = (const float*)d_in[25];
  const float* tl_b    = (const float*)d_in[26];
  const float* plo_ln_s= (const float*)d_in[27];
  const float* plo_ln_b= (const float*)d_in[28];
  const float* plo_W   = (const float*)d_in[29];
  const float* plo_b   = (const float*)d_in[30];
  const float* gn_s    = (const float*)d_in[31];
  const float* gn_b    = (const float*)d_in[32];
  const float* conv_W  = (const float*)d_in[33];
  const float* conv_b  = (const float*)d_in[34];

  float* ws    = (float*)d_ws;
  float* e     = ws;                        // 16,777,216 floats
  float* x     = e + (size_t)NROWS*128;
  float* Uh    = x + 65536;
  float* Vh    = Uh + 65536;
  float* Ax    = Vh + 65536;
  float* Bx    = Ax + 65536;
  float* tproj = Bx + 65536;                // 1024
  float* sraw  = tproj + 1024;              // 128
  float* stats = sraw + 128;                // 128
  float* aggP  = stats + 128;               // 1024*8*128 = 1,048,576
  u16*   WTC   = (u16*)(aggP + 1048576);    // 4*16384 u16
  u16*   WTP   = WTC + (size_t)LL*16384;
  u16*   WTE   = WTP + (size_t)LL*16384;    // 16384 u16

  k_zero<<<1, 128, 0, stream>>>(sraw);
  k_wprep<<<512, 256, 0, stream>>>(C_W, plo_W, WTC, WTP);
  k_wprep_e<<<64, 256, 0, stream>>>(edge_W, WTE);
  k_time<<<1, 512, 0, stream>>>(t, te1_W, te1_b, te2_W, te2_b, tl_W, tl_b, tproj);
  k_node_embed<<<8, 256, 0, stream>>>(coords, node_W, node_b, x);
  k_edge_embed2<<<NROWS/64, 256, 0, stream>>>(adj_t, WTE, edge_b, e);

  for (int i = 0; i < LL; ++i) {
    k_node4<<<BB*NN, 128, 0, stream>>>(x,
        U_W + (size_t)i*16384, U_b + i*128,
        V_W + (size_t)i*16384, V_b + i*128,
        A_W + (size_t)i*16384, A_b + i*128,
        B_W + (size_t)i*16384, B_b + i*128,
        Uh, Vh, Ax, Bx);
    k_layer<<<NROWS/128, 512, 0, stream>>>(e,
        WTC + (size_t)i*16384, WTP + (size_t)i*16384,
        C_b + i*128, Ax, Bx, Vh,
        lne_s + i*128, lne_b + i*128,
        tproj + i*BB*128,
        plo_ln_s + i*128, plo_ln_b + i*128, plo_b + i*128,
        aggP);
    k_xupd<<<BB*NN, 128, 0, stream>>>(aggP, Uh, lnh_s + i*128, lnh_b + i*128, x);
  }

  k_gnstats2<<<512, 256, 0, stream>>>(e, sraw);
  k_gnfin<<<1, 64, 0, stream>>>(sraw, stats);
  k_out<<<NROWS/64, 256, 0, stream>>>(e, stats, gn_s, gn_b, conv_W, conv_b,
                                      (float*)d_out);
}

// Round 20
// 411.246 us; speedup vs baseline: 1.0419x; 1.0419x over previous
//
#include <hip/hip_runtime.h>
#include <hip/hip_bf16.h>

typedef unsigned short u16;
typedef __attribute__((ext_vector_type(8))) short short8;
typedef __attribute__((ext_vector_type(8))) unsigned short ushort8;
typedef __attribute__((ext_vector_type(4))) float f32x4;

#define BB 2
#define NN 256
#define DD 128
#define TDD 64
#define LL 4
#define NGROUP 32
#define NROWS (BB*NN*NN)      // 131072 edge rows
#define LDS_STR 68            // padded LDS stride for fp32 embed kernels

#define LOG1E4 9.210340371976184f
#define TWO_PI 6.283185307179586f

// ---------------- fp32 tile GEMM (node embed kernel only) ----------------
#define TILE_GEMM(AT, WPTR, ACC) do {                                          \
  _Pragma("unroll 4")                                                          \
  for (int k = 0; k < 128; ++k) {                                              \
    const float4 w4 = *reinterpret_cast<const float4*>((WPTR) + k*128 + tx*4); \
    const float4 a0 = *reinterpret_cast<const float4*>(&(AT)[k*LDS_STR + ty*8]);     \
    const float4 a1 = *reinterpret_cast<const float4*>(&(AT)[k*LDS_STR + ty*8 + 4]); \
    const float av[8] = {a0.x,a0.y,a0.z,a0.w,a1.x,a1.y,a1.z,a1.w};             \
    const float wv[4] = {w4.x,w4.y,w4.z,w4.w};                                 \
    _Pragma("unroll") for (int r = 0; r < 8; ++r)                              \
      _Pragma("unroll") for (int c = 0; c < 4; ++c)                            \
        ACC[r][c] += av[r]*wv[c];                                              \
  }                                                                            \
} while (0)

__device__ __forceinline__ float sigmoidf_(float x) {
  return 1.f / (1.f + __expf(-x));
}

// round-to-nearest-even f32 -> bf16 bits (proven r3-r17)
__device__ __forceinline__ u16 f2bf(float f) {
  union { float f; unsigned int u; } c; c.f = f;
  unsigned int r = (c.u + 0x7FFFu + ((c.u >> 16) & 1u)) >> 16;
  return (u16)r;
}

// ---- time embedding pipeline -> tproj[L][B][D] (parallel over b, unrolled) ----
__global__ __launch_bounds__(512) void k_time(
    const float* __restrict__ t,
    const float* __restrict__ te1_W, const float* __restrict__ te1_b,
    const float* __restrict__ te2_W, const float* __restrict__ te2_b,
    const float* __restrict__ tl_W,  const float* __restrict__ tl_b,
    float* __restrict__ tproj) {
  __shared__ float temb[BB][128], h1[BB][64], rt[BB][64];
  const int tid = threadIdx.x;
  const int b  = tid >> 8;           // 0..1
  const int t2 = tid & 255;          // 0..255 within batch group
  const float tv = t[b];
  if (t2 < 128) {
    int j = t2 & 63;
    float f = expf(-LOG1E4 * (float)j / 64.f);
    float a = tv * f;
    temb[b][t2] = (t2 < 64) ? cosf(a) : sinf(a);
  }
  __syncthreads();
  if (t2 < 64) {
    float acc = te1_b[t2];
#pragma unroll
    for (int k = 0; k < 128; ++k) acc += temb[b][k] * te1_W[k*64 + t2];
    h1[b][t2] = fmaxf(acc, 0.f);
  }
  __syncthreads();
  if (t2 < 64) {
    float acc = te2_b[t2];
#pragma unroll
    for (int k = 0; k < 64; ++k) acc += h1[b][k] * te2_W[k*64 + t2];
    rt[b][t2] = fmaxf(acc, 0.f);     // relu(te)
  }
  __syncthreads();
  if (t2 < 128) {
#pragma unroll
    for (int i = 0; i < LL; ++i) {
      float acc = tl_b[i*128 + t2];
#pragma unroll
      for (int k = 0; k < 64; ++k) acc += rt[b][k] * tl_W[(i*64 + k)*128 + t2];
      tproj[(i*BB + b)*128 + t2] = acc;
    }
  }
}

// ---------------- node pos-embed + node_W GEMM -> x (512 x 128) ----------------
__global__ __launch_bounds__(256) void k_node_embed(
    const float* __restrict__ coords, const float* __restrict__ W,
    const float* __restrict__ bias, float* __restrict__ x_out) {
  __shared__ float at[128*LDS_STR];
  int tid = threadIdx.x;
  int row = tid >> 2, part = tid & 3;
  int R = blockIdx.x*64 + row;
  float cy = coords[R*2 + 0], cx = coords[R*2 + 1];
#pragma unroll
  for (int q = 0; q < 32; ++q) {
    int c = part*32 + q;
    int k = (c < 64) ? c : c - 64;
    float v = (c < 64) ? cy : cx;
    int m = k >> 1;
    float inv = __expf(-LOG1E4 * (float)m / 32.f);
    float a = v * TWO_PI * inv;
    at[c*LDS_STR + row] = (k & 1) ? __cosf(a) : __sinf(a);
  }
  __syncthreads();
  int tx = tid & 31, ty = tid >> 5;
  float acc[8][4] = {};
  TILE_GEMM(at, W, acc);
  float4 bb4 = *reinterpret_cast<const float4*>(bias + tx*4);
#pragma unroll
  for (int r = 0; r < 8; ++r) {
    int R2 = blockIdx.x*64 + ty*8 + r;
    float4 o = {acc[r][0]+bb4.x, acc[r][1]+bb4.y, acc[r][2]+bb4.z, acc[r][3]+bb4.w};
    *reinterpret_cast<float4*>(x_out + (size_t)R2*128 + tx*4) = o;
  }
}

// ------- edge_W^T bf16 prep for MFMA edge embed: WTE[n][k] -------
__global__ __launch_bounds__(256) void k_wprep_e(
    const float* __restrict__ EW, u16* __restrict__ WTE) {
  int idx = blockIdx.x*256 + threadIdx.x;    // 0..16383
  int n = idx >> 7, k = idx & 127;
  WTE[n*128 + k] = f2bf(EW[(size_t)k*128 + n]);
}

// ------- MFMA edge pos-embed: e = posembed(adj) @ edge_W + edge_b -------
__global__ __launch_bounds__(256, 3) void k_edge_embed2(
    const float* __restrict__ adj, const u16* __restrict__ WTE,
    const float* __restrict__ bias, float* __restrict__ e_out) {
  __shared__ __align__(16) u16 Abuf[64*128];    // 16 KB pos-embed bf16
  __shared__ __align__(16) u16 Wbuf[128*128];   // 32 KB edge_W^T

  const int tid = threadIdx.x;
  const int blk = blockIdx.x;
  const int w  = tid >> 6;
  const int l  = tid & 63;
  const int lg = l >> 4;
  const int ln = l & 15;

  {
    const int r = tid >> 1, h = tid & 1;
    const int r7 = r & 7;
    const u16* src = WTE + r*128;
    u16* dst = Wbuf + r*128;
#pragma unroll
    for (int q = 0; q < 8; ++q) {
      int c = h*8 + q;
      short8 v = *reinterpret_cast<const short8*>(src + c*8);
      *reinterpret_cast<short8*>(dst + ((c ^ r7) << 3)) = v;
    }
  }
  {
    const int r = tid >> 2;          // 0..63
    const int p = tid & 3;
    const float v = adj[(size_t)blk*64 + r];
    const int r7 = r & 7;
    u16* arow = Abuf + r*128;
#pragma unroll
    for (int q = 0; q < 4; ++q) {
      u16 h8[8];
#pragma unroll
      for (int j = 0; j < 8; ++j) {
        int k = (p*4 + q)*8 + j;     // column 0..127
        int m = k >> 1;
        float inv = __expf(-LOG1E4 * (float)m / 64.f);
        float a = v * inv;
        h8[j] = f2bf((k & 1) ? __cosf(a) : __sinf(a));
      }
      int pc = (p*4 + q) ^ r7;
      *reinterpret_cast<ushort8*>(arow + pc*8) = *reinterpret_cast<ushort8*>(h8);
    }
  }
  __syncthreads();

  f32x4 acc[8];
#pragma unroll
  for (int nt = 0; nt < 8; ++nt) {
    const float bv = bias[nt*16 + ln];
#pragma unroll
    for (int rg = 0; rg < 4; ++rg) acc[nt][rg] = bv;
  }
  {
    const u16* arow = Abuf + (w*16 + ln)*128;
    const int r7 = ln & 7;
#pragma unroll
    for (int ks = 0; ks < 4; ++ks) {
      short8 a = *reinterpret_cast<const short8*>(arow + (((ks*4 + lg) ^ r7) << 3));
#pragma unroll
      for (int nt = 0; nt < 8; ++nt) {
        short8 bw = *reinterpret_cast<const short8*>(
            Wbuf + (nt*16 + ln)*128 + (((ks*4 + lg) ^ (ln & 7)) << 3));
        acc[nt] = __builtin_amdgcn_mfma_f32_16x16x32_bf16(a, bw, acc[nt], 0, 0, 0);
      }
    }
  }
#pragma unroll
  for (int nt = 0; nt < 8; ++nt)
#pragma unroll
    for (int rg = 0; rg < 4; ++rg)
      e_out[((size_t)blk*64 + w*16 + lg*4 + rg)*128 + nt*16 + ln] = acc[nt][rg];
}

// ---------------- per-layer node linears: Uh,Vh,Ax,Bx (512 rows) ----------------
__global__ __launch_bounds__(128) void k_node4(
    const float* __restrict__ x,
    const float* __restrict__ UW, const float* __restrict__ Ub,
    const float* __restrict__ VW, const float* __restrict__ Vb,
    const float* __restrict__ AW, const float* __restrict__ Ab,
    const float* __restrict__ BW, const float* __restrict__ Bb,
    float* __restrict__ Uh, float* __restrict__ Vh,
    float* __restrict__ Axo, float* __restrict__ Bxo) {
  __shared__ float xr[128];
  int R = blockIdx.x, d = threadIdx.x;
  xr[d] = x[(size_t)R*128 + d];
  __syncthreads();
  float au = Ub[d], av = Vb[d], aa = Ab[d], ab = Bb[d];
  for (int k = 0; k < 128; ++k) {
    float xv = xr[k];
    au += xv * UW[k*128 + d];
    av += xv * VW[k*128 + d];
    aa += xv * AW[k*128 + d];
    ab += xv * BW[k*128 + d];
  }
  Uh[(size_t)R*128 + d] = au;
  Vh[(size_t)R*128 + d] = av;
  Axo[(size_t)R*128 + d] = aa;
  Bxo[(size_t)R*128 + d] = ab;
}

// ===== fused x-update + next-layer node linears (per node) =====
// Phase 1 = k_xupd (layer i-1 LN params); phase 2 = k_node4 (layer i weights).
// Uh is read (old) in phase 1 before being overwritten in phase 2 (same block).
__global__ __launch_bounds__(128) void k_xnode(
    const float* __restrict__ aggP,
    const float* __restrict__ lnh_s, const float* __restrict__ lnh_b,
    float* __restrict__ x,
    const float* __restrict__ UW, const float* __restrict__ Ub,
    const float* __restrict__ VW, const float* __restrict__ Vb,
    const float* __restrict__ AW, const float* __restrict__ Ab,
    const float* __restrict__ BW, const float* __restrict__ Bb,
    float* __restrict__ Uh, float* __restrict__ Vh,
    float* __restrict__ Axo, float* __restrict__ Bxo) {
  __shared__ float xr[128];
  __shared__ float red[4];
  int bi = blockIdx.x, d = threadIdx.x;
  // ---- phase 1: x += relu(LN(Uh_old + agg)) ----
  float u = Uh[(size_t)bi*128 + d];
#pragma unroll
  for (int st = 0; st < 16; ++st) u += aggP[((size_t)bi*16 + st)*128 + d];
  float s = u, s2 = u*u;
#pragma unroll
  for (int m = 1; m <= 32; m <<= 1) { s += __shfl_xor(s, m); s2 += __shfl_xor(s2, m); }
  int wid = d >> 6;
  if ((d & 63) == 0) { red[wid] = s; red[2 + wid] = s2; }
  __syncthreads();
  s = red[0] + red[1];  s2 = red[2] + red[3];
  float mean = s * (1.f/128.f);
  float rs = rsqrtf(s2 * (1.f/128.f) - mean*mean + 1e-5f);
  float xv = x[(size_t)bi*128 + d] + fmaxf((u - mean)*rs*lnh_s[d] + lnh_b[d], 0.f);
  x[(size_t)bi*128 + d] = xv;
  xr[d] = xv;
  __syncthreads();
  // ---- phase 2: next layer's 4 GEMVs from LDS ----
  float au = Ub[d], av = Vb[d], aa = Ab[d], ab = Bb[d];
  for (int k = 0; k < 128; ++k) {
    float xk = xr[k];
    au += xk * UW[k*128 + d];
    av += xk * VW[k*128 + d];
    aa += xk * AW[k*128 + d];
    ab += xk * BW[k*128 + d];
  }
  Uh[(size_t)bi*128 + d] = au;
  Vh[(size_t)bi*128 + d] = av;
  Axo[(size_t)bi*128 + d] = aa;
  Bxo[(size_t)bi*128 + d] = ab;
}

// ---------------- weight prep: bf16 transposed copies WT[n][k] ----------------
__global__ __launch_bounds__(256) void k_wprep(
    const float* __restrict__ CW, const float* __restrict__ PW,
    u16* __restrict__ WTC, u16* __restrict__ WTP) {
  int idx = blockIdx.x*256 + threadIdx.x;    // 0..131071
  int m = idx >> 14;                          // 0..7 (layer*2 + type)
  int r = idx & 16383;
  int layer = m >> 1;
  int n = r >> 7, k = r & 127;
  if ((m & 1) == 0)
    WTC[layer*16384 + n*128 + k] = f2bf(CW[(size_t)layer*16384 + k*128 + n]);
  else
    WTP[layer*16384 + n*128 + k] = f2bf(PW[(size_t)layer*16384 + k*128 + n]);
}

// ===== fused per-layer MFMA kernel: 512-thr / 128-row blocks (r17 EXACT) =====
__global__ __launch_bounds__(512, 2) void k_layer(
    float* __restrict__ e,
    const u16* __restrict__ WTC, const u16* __restrict__ WTP,
    const float* __restrict__ Cb, const float* __restrict__ Ax,
    const float* __restrict__ Bx, const float* __restrict__ Vh,
    const float* __restrict__ lnes_g, const float* __restrict__ lneb_g,
    const float* __restrict__ tp_g,
    const float* __restrict__ plos_g, const float* __restrict__ plobl_g,
    const float* __restrict__ plob_g,
    float* __restrict__ aggP) {

  __shared__ __align__(16) u16 Abuf[128*128];   // 32 KB (e, then sv)
  __shared__ __align__(16) u16 Wbuf[128*128];   // 32 KB (WTC, then WTP)

  const int tid = threadIdx.x;
  const int blk0 = blockIdx.x;
  const int blk = ((blk0 & 7) << 7) | (blk0 >> 3);   // XCD swizzle (1024%8==0)
  const int bi  = blk >> 1;          // b*256 + i
  const int b   = bi >> 8;
  const int jh  = blk & 1;           // 128-row half
  const size_t rbase = (size_t)bi*256 + jh*128;

  const int w  = tid >> 6;           // 0..7
  const int l  = tid & 63;
  const int lg = l >> 4;             // 0..3
  const int ln = l & 15;             // 0..15

  // ---- stage e tile -> bf16 Abuf (chunk ^ (row&7) swizzle) ----
  {
    const int r = tid >> 2;          // 0..127
    const int p = tid & 3;
    const float* src = e + (rbase + r)*128 + p*32;
    const int r7 = r & 7;
    u16* arow = Abuf + r*128;
#pragma unroll
    for (int q = 0; q < 4; ++q) {
      float4 f0 = *reinterpret_cast<const float4*>(src + q*8);
      float4 f1 = *reinterpret_cast<const float4*>(src + q*8 + 4);
      int pc = (p*4 + q) ^ r7;
      ushort8 h = {f2bf(f0.x),f2bf(f0.y),f2bf(f0.z),f2bf(f0.w),
                   f2bf(f1.x),f2bf(f1.y),f2bf(f1.z),f2bf(f1.w)};
      *reinterpret_cast<ushort8*>(arow + pc*8) = h;
    }
  }
  // ---- stage WTC -> Wbuf (swizzled), 4 threads per row ----
  {
    const int r = tid >> 2;          // 0..127
    const int h = tid & 3;
    const int r7 = r & 7;
    const u16* src = WTC + r*128;
    u16* dst = Wbuf + r*128;
#pragma unroll
    for (int q = 0; q < 4; ++q) {
      int c = h*4 + q;               // 16B chunk index 0..15
      short8 v = *reinterpret_cast<const short8*>(src + c*8);
      *reinterpret_cast<short8*>(dst + ((c ^ r7) << 3)) = v;
    }
  }
  __syncthreads();   // barrier 1: Wbuf + Abuf visible

  const int lrow0 = w*16 + lg*4;           // lane's first row, tile-local
  const int jrow0 = jh*128 + lrow0;        // same, node-local

  // ---- gate init: Cb + Ax[i] + Bx[j] ----
  f32x4 acc[8];
#pragma unroll
  for (int nt = 0; nt < 8; ++nt) {
    const int c = nt*16 + ln;
    const float cbax = Cb[c] + Ax[(size_t)bi*128 + c];
#pragma unroll
    for (int rg = 0; rg < 4; ++rg)
      acc[nt][rg] = cbax + Bx[((size_t)b*256 + jrow0 + rg)*128 + c];
  }

  // ---- GEMM1: += e @ C_W (A and B both from LDS) ----
  {
    const u16* arow = Abuf + (w*16 + ln)*128;
    const int r7 = ln & 7;
#pragma unroll
    for (int ks = 0; ks < 4; ++ks) {
      short8 a = *reinterpret_cast<const short8*>(arow + (((ks*4 + lg) ^ r7) << 3));
#pragma unroll
      for (int nt = 0; nt < 8; ++nt) {
        short8 bw = *reinterpret_cast<const short8*>(
            Wbuf + (nt*16 + ln)*128 + (((ks*4 + lg) ^ (ln & 7)) << 3));
        acc[nt] = __builtin_amdgcn_mfma_f32_16x16x32_bf16(a, bw, acc[nt], 0, 0, 0);
      }
    }
  }

  // ---- per-row pipeline: agg, LN1+relu+tproj, LN2+silu -> sv to Abuf ----
  float av[8] = {0.f,0.f,0.f,0.f,0.f,0.f,0.f,0.f};
  float tp_[8], ls_[8], lb_[8], ps_[8], pl_[8];
#pragma unroll
  for (int nt = 0; nt < 8; ++nt) {
    const int c = nt*16 + ln;
    tp_[nt] = tp_g[b*128 + c];
    ls_[nt] = lnes_g[c];  lb_[nt] = lneb_g[c];
    ps_[nt] = plos_g[c];  pl_[nt] = plobl_g[c];
  }

#pragma unroll
  for (int rg = 0; rg < 4; ++rg) {
    float ss = 0.f, s2 = 0.f;
#pragma unroll
    for (int nt = 0; nt < 8; ++nt) { float g = acc[nt][rg]; ss += g; s2 += g*g; }
    ss += __shfl_xor(ss, 1);  s2 += __shfl_xor(s2, 1);
    ss += __shfl_xor(ss, 2);  s2 += __shfl_xor(s2, 2);
    ss += __shfl_xor(ss, 4);  s2 += __shfl_xor(s2, 4);
    ss += __shfl_xor(ss, 8);  s2 += __shfl_xor(s2, 8);
    const float mean = ss * (1.f/128.f);
    const float rs = rsqrtf(s2 * (1.f/128.f) - mean*mean + 1e-5f);
    const size_t vrow = ((size_t)b*256 + jrow0 + rg)*128;
    float s3 = 0.f, s4 = 0.f;
#pragma unroll
    for (int nt = 0; nt < 8; ++nt) {
      const float g = acc[nt][rg];
      av[nt] += Vh[vrow + nt*16 + ln] * sigmoidf_(g);
      float tv = fmaxf((g - mean)*rs*ls_[nt] + lb_[nt], 0.f) + tp_[nt];
      acc[nt][rg] = tv;
      s3 += tv;  s4 += tv*tv;
    }
    s3 += __shfl_xor(s3, 1);  s4 += __shfl_xor(s4, 1);
    s3 += __shfl_xor(s3, 2);  s4 += __shfl_xor(s4, 2);
    s3 += __shfl_xor(s3, 4);  s4 += __shfl_xor(s4, 4);
    s3 += __shfl_xor(s3, 8);  s4 += __shfl_xor(s4, 8);
    const float mean2 = s3 * (1.f/128.f);
    const float rs2 = rsqrtf(s4 * (1.f/128.f) - mean2*mean2 + 1e-5f);
    const int rr = lrow0 + rg;
    const int rr7 = rr & 7;
#pragma unroll
    for (int nt = 0; nt < 8; ++nt) {
      float vv = (acc[nt][rg] - mean2)*rs2*ps_[nt] + pl_[nt];
      vv = vv * sigmoidf_(vv);
      const int cc = nt*16 + ln;
      const int pc = (cc >> 3) ^ rr7;
      Abuf[rr*128 + pc*8 + (cc & 7)] = f2bf(vv);
    }
  }

  // ---- all waves done with Wbuf(WTC); restage WTP ----
  __syncthreads();
  {
    const int r = tid >> 2;
    const int h = tid & 3;
    const int r7 = r & 7;
    const u16* src = WTP + r*128;
    u16* dst = Wbuf + r*128;
#pragma unroll
    for (int q = 0; q < 4; ++q) {
      int c = h*4 + q;
      short8 v = *reinterpret_cast<const short8*>(src + c*8);
      *reinterpret_cast<short8*>(dst + ((c ^ r7) << 3)) = v;
    }
  }
  __syncthreads();

  // ---- GEMM2: acc2 = sv @ plo_W ----
  f32x4 acc2[8];
#pragma unroll
  for (int nt = 0; nt < 8; ++nt) acc2[nt] = (f32x4)(0.f);
  {
    const u16* arow = Abuf + (w*16 + ln)*128;
    const int r7 = ln & 7;
#pragma unroll
    for (int ks = 0; ks < 4; ++ks) {
      short8 a = *reinterpret_cast<const short8*>(arow + (((ks*4 + lg) ^ r7) << 3));
#pragma unroll
      for (int nt = 0; nt < 8; ++nt) {
        short8 bw = *reinterpret_cast<const short8*>(
            Wbuf + (nt*16 + ln)*128 + (((ks*4 + lg) ^ (ln & 7)) << 3));
        acc2[nt] = __builtin_amdgcn_mfma_f32_16x16x32_bf16(a, bw, acc2[nt], 0, 0, 0);
      }
    }
  }

  // ---- e += acc2 + plo_b  (RMW; residual read L2/L3-hot) ----
#pragma unroll
  for (int nt = 0; nt < 8; ++nt) {
    const float pbv = plob_g[nt*16 + ln];
#pragma unroll
    for (int rg = 0; rg < 4; ++rg) {
      float* ep = e + (rbase + lrow0 + rg)*128 + nt*16 + ln;
      *ep = *ep + acc2[nt][rg] + pbv;
    }
  }

  // ---- agg: reduce lane partials over wave's 16 rows ----
#pragma unroll
  for (int nt = 0; nt < 8; ++nt) {
    float v = av[nt];
    v += __shfl_xor(v, 16);
    v += __shfl_xor(v, 32);
    av[nt] = v;
  }
  if (lg == 0) {
#pragma unroll
    for (int nt = 0; nt < 8; ++nt)
      aggP[((size_t)blk*8 + w)*128 + nt*16 + ln] = av[nt];
  }
}

// ---------------- x update: x += relu(LN(Uh + agg)) (final layer only) --------
__global__ __launch_bounds__(128) void k_xupd(
    const float* __restrict__ aggP, const float* __restrict__ Uh,
    const float* __restrict__ lnh_s, const float* __restrict__ lnh_b,
    float* __restrict__ x) {
  int bi = blockIdx.x, d = threadIdx.x;
  float u = Uh[(size_t)bi*128 + d];
#pragma unroll
  for (int st = 0; st < 16; ++st) u += aggP[((size_t)bi*16 + st)*128 + d];
  float s = u, s2 = u*u;
#pragma unroll
  for (int m = 1; m <= 32; m <<= 1) { s += __shfl_xor(s, m); s2 += __shfl_xor(s2, m); }
  __shared__ float red[4];
  int wid = d >> 6;
  if ((d & 63) == 0) { red[wid] = s; red[2 + wid] = s2; }
  __syncthreads();
  s = red[0] + red[1];  s2 = red[2] + red[3];
  float mean = s * (1.f/128.f);
  float rs = rsqrtf(s2 * (1.f/128.f) - mean*mean + 1e-5f);
  x[(size_t)bi*128 + d] += fmaxf((u - mean)*rs*lnh_s[d] + lnh_b[d], 0.f);
}

// ---------------- zero the GN stats accumulators ----------------
__global__ __launch_bounds__(128) void k_zero(float* __restrict__ p) {
  p[threadIdx.x] = 0.f;
}

// ---------- GN stats, group-aligned: one float4 = one group ----------
__global__ __launch_bounds__(256) void k_gnstats2(
    const float* __restrict__ e, float* __restrict__ sraw) {
  const int blk = blockIdx.x;      // 512 blocks x 256 rows
  const int b = blk >> 8;
  const int c = threadIdx.x & 31;  // group == float4 chunk
  const int r0 = threadIdx.x >> 5; // 0..7
  float s = 0.f, s2 = 0.f;
  for (int it = 0; it < 32; ++it) {
    size_t row = (size_t)blk*256 + it*8 + r0;
    float4 f = *reinterpret_cast<const float4*>(e + row*128 + c*4);
    s  += f.x + f.y + f.z + f.w;
    s2 += f.x*f.x + f.y*f.y + f.z*f.z + f.w*f.w;
  }
  __shared__ float red[256], red2[256];
  red[threadIdx.x] = s;  red2[threadIdx.x] = s2;
  __syncthreads();
  if (threadIdx.x < 32) {
    float S = 0.f, S2 = 0.f;
#pragma unroll
    for (int k = 0; k < 8; ++k) { S += red[k*32 + threadIdx.x]; S2 += red2[k*32 + threadIdx.x]; }
    atomicAdd(&sraw[((size_t)b*32 + threadIdx.x)*2],     S);
    atomicAdd(&sraw[((size_t)b*32 + threadIdx.x)*2 + 1], S2);
  }
}

// ---------------- finalize GN stats ----------------
__global__ __launch_bounds__(64) void k_gnfin(
    const float* __restrict__ raw, float* __restrict__ stats) {
  int i = threadIdx.x;
  const float cnt = (float)(NN*NN*4);
  float S  = raw[i*2];
  float S2 = raw[i*2 + 1];
  float mean = S / cnt;
  float var = S2 / cnt - mean*mean;
  stats[i*2]     = mean;
  stats[i*2 + 1] = rsqrtf(var + 1e-5f);
}

// ---------------- final: out = relu(gn(e)) . conv_W + conv_b ----------------
__global__ __launch_bounds__(256) void k_out(
    const float* __restrict__ e, const float* __restrict__ stats,
    const float* __restrict__ gn_s, const float* __restrict__ gn_b,
    const float* __restrict__ convW, const float* __restrict__ convb,
    float* __restrict__ out) {
  int tid = threadIdx.x;
  int row = tid >> 2, part = tid & 3;
  size_t R = (size_t)blockIdx.x*64 + row;
  size_t b = R >> 16;
  float acc = 0.f;
  const float4* er = reinterpret_cast<const float4*>(e + R*128 + part*32);
#pragma unroll
  for (int q = 0; q < 8; ++q) {
    float4 f = er[q];
    float fv[4] = {f.x, f.y, f.z, f.w};
#pragma unroll
    for (int lidx = 0; lidx < 4; ++lidx) {
      int c = part*32 + q*4 + lidx;
      int g = c >> 2;
      float mean = stats[(b*NGROUP + g)*2 + 0];
      float rs   = stats[(b*NGROUP + g)*2 + 1];
      float t = (fv[lidx] - mean)*rs*gn_s[c] + gn_b[c];
      acc += fmaxf(t, 0.f) * convW[c];
    }
  }
  acc += __shfl_xor(acc, 1);
  acc += __shfl_xor(acc, 2);
  if (part == 0) out[R] = acc + convb[0];
}

extern "C" void kernel_launch(void* const* d_in, const int* in_sizes, int n_in,
                              void* d_out, int out_size, void* d_ws, size_t ws_size,
                              hipStream_t stream) {
  const float* coords  = (const float*)d_in[0];
  const float* adj_t   = (const float*)d_in[1];
  const float* t       = (const float*)d_in[2];
  const float* node_W  = (const float*)d_in[3];
  const float* node_b  = (const float*)d_in[4];
  const float* edge_W  = (const float*)d_in[5];
  const float* edge_b  = (const float*)d_in[6];
  const float* te1_W   = (const float*)d_in[7];
  const float* te1_b   = (const float*)d_in[8];
  const float* te2_W   = (const float*)d_in[9];
  const float* te2_b   = (const float*)d_in[10];
  const float* A_W     = (const float*)d_in[11];
  const float* A_b     = (const float*)d_in[12];
  const float* B_W     = (const float*)d_in[13];
  const float* B_b     = (const float*)d_in[14];
  const float* C_W     = (const float*)d_in[15];
  const float* C_b     = (const float*)d_in[16];
  const float* U_W     = (const float*)d_in[17];
  const float* U_b     = (const float*)d_in[18];
  const float* V_W     = (const float*)d_in[19];
  const float* V_b     = (const float*)d_in[20];
  const float* lnh_s   = (const float*)d_in[21];
  const float* lnh_b   = (const float*)d_in[22];
  const float* lne_s   = (const float*)d_in[23];
  const float* lne_b   = (const float*)d_in[24];
  const float* tl_W    = (const float*)d_in[25];
  const float* tl_b    = (const float*)d_in[26];
  const float* plo_ln_s= (const float*)d_in[27];
  const float* plo_ln_b= (const float*)d_in[28];
  const float* plo_W   = (const float*)d_in[29];
  const float* plo_b   = (const float*)d_in[30];
  const float* gn_s    = (const float*)d_in[31];
  const float* gn_b    = (const float*)d_in[32];
  const float* conv_W  = (const float*)d_in[33];
  const float* conv_b  = (const float*)d_in[34];

  float* ws    = (float*)d_ws;
  float* e     = ws;                        // 16,777,216 floats
  float* x     = e + (size_t)NROWS*128;
  float* Uh    = x + 65536;
  float* Vh    = Uh + 65536;
  float* Ax    = Vh + 65536;
  float* Bx    = Ax + 65536;
  float* tproj = Bx + 65536;                // 1024
  float* sraw  = tproj + 1024;              // 128
  float* stats = sraw + 128;                // 128
  float* aggP  = stats + 128;               // 1024*8*128 = 1,048,576
  u16*   WTC   = (u16*)(aggP + 1048576);    // 4*16384 u16
  u16*   WTP   = WTC + (size_t)LL*16384;
  u16*   WTE   = WTP + (size_t)LL*16384;    // 16384 u16

  k_zero<<<1, 128, 0, stream>>>(sraw);
  k_wprep<<<512, 256, 0, stream>>>(C_W, plo_W, WTC, WTP);
  k_wprep_e<<<64, 256, 0, stream>>>(edge_W, WTE);
  k_time<<<1, 512, 0, stream>>>(t, te1_W, te1_b, te2_W, te2_b, tl_W, tl_b, tproj);
  k_node_embed<<<8, 256, 0, stream>>>(coords, node_W, node_b, x);
  k_edge_embed2<<<NROWS/64, 256, 0, stream>>>(adj_t, WTE, edge_b, e);

  for (int i = 0; i < LL; ++i) {
    if (i == 0) {
      k_node4<<<BB*NN, 128, 0, stream>>>(x,
          U_W, U_b, V_W, V_b, A_W, A_b, B_W, B_b,
          Uh, Vh, Ax, Bx);
    } else {
      k_xnode<<<BB*NN, 128, 0, stream>>>(aggP,
          lnh_s + (i-1)*128, lnh_b + (i-1)*128, x,
          U_W + (size_t)i*16384, U_b + i*128,
          V_W + (size_t)i*16384, V_b + i*128,
          A_W + (size_t)i*16384, A_b + i*128,
          B_W + (size_t)i*16384, B_b + i*128,
          Uh, Vh, Ax, Bx);
    }
    k_layer<<<NROWS/128, 512, 0, stream>>>(e,
        WTC + (size_t)i*16384, WTP + (size_t)i*16384,
        C_b + i*128, Ax, Bx, Vh,
        lne_s + i*128, lne_b + i*128,
        tproj + i*BB*128,
        plo_ln_s + i*128, plo_ln_b + i*128, plo_b + i*128,
        aggP);
  }
  k_xupd<<<BB*NN, 128, 0, stream>>>(aggP, Uh, lnh_s + 3*128, lnh_b + 3*128, x);

  k_gnstats2<<<512, 256, 0, stream>>>(e, sraw);
  k_gnfin<<<1, 64, 0, stream>>>(sraw, stats);
  k_out<<<NROWS/64, 256, 0, stream>>>(e, stats, gn_s, gn_b, conv_W, conv_b,
                                      (float*)d_out);
}

// Round 21
// 396.529 us; speedup vs baseline: 1.0805x; 1.0371x over previous
//
#include <hip/hip_runtime.h>
#include <hip/hip_bf16.h>

typedef unsigned short u16;
typedef __attribute__((ext_vector_type(8))) short short8;
typedef __attribute__((ext_vector_type(8))) unsigned short ushort8;
typedef __attribute__((ext_vector_type(4))) float f32x4;

#define BB 2
#define NN 256
#define DD 128
#define TDD 64
#define LL 4
#define NGROUP 32
#define NROWS (BB*NN*NN)      // 131072 edge rows
#define LDS_STR 68            // padded LDS stride for fp32 embed kernels

#define LOG1E4 9.210340371976184f
#define TWO_PI 6.283185307179586f

// ---------------- fp32 tile GEMM (node embed kernel only) ----------------
#define TILE_GEMM(AT, WPTR, ACC) do {                                          \
  _Pragma("unroll 4")                                                          \
  for (int k = 0; k < 128; ++k) {                                              \
    const float4 w4 = *reinterpret_cast<const float4*>((WPTR) + k*128 + tx*4); \
    const float4 a0 = *reinterpret_cast<const float4*>(&(AT)[k*LDS_STR + ty*8]);     \
    const float4 a1 = *reinterpret_cast<const float4*>(&(AT)[k*LDS_STR + ty*8 + 4]); \
    const float av[8] = {a0.x,a0.y,a0.z,a0.w,a1.x,a1.y,a1.z,a1.w};             \
    const float wv[4] = {w4.x,w4.y,w4.z,w4.w};                                 \
    _Pragma("unroll") for (int r = 0; r < 8; ++r)                              \
      _Pragma("unroll") for (int c = 0; c < 4; ++c)                            \
        ACC[r][c] += av[r]*wv[c];                                              \
  }                                                                            \
} while (0)

__device__ __forceinline__ float sigmoidf_(float x) {
  return 1.f / (1.f + __expf(-x));
}

// round-to-nearest-even f32 -> bf16 bits (proven r3-r17)
__device__ __forceinline__ u16 f2bf(float f) {
  union { float f; unsigned int u; } c; c.f = f;
  unsigned int r = (c.u + 0x7FFFu + ((c.u >> 16) & 1u)) >> 16;
  return (u16)r;
}

// ---- time embedding pipeline -> tproj[L][B][D] (parallel over b, unrolled) ----
__global__ __launch_bounds__(512) void k_time(
    const float* __restrict__ t,
    const float* __restrict__ te1_W, const float* __restrict__ te1_b,
    const float* __restrict__ te2_W, const float* __restrict__ te2_b,
    const float* __restrict__ tl_W,  const float* __restrict__ tl_b,
    float* __restrict__ tproj) {
  __shared__ float temb[BB][128], h1[BB][64], rt[BB][64];
  const int tid = threadIdx.x;
  const int b  = tid >> 8;           // 0..1
  const int t2 = tid & 255;          // 0..255 within batch group
  const float tv = t[b];
  if (t2 < 128) {
    int j = t2 & 63;
    float f = expf(-LOG1E4 * (float)j / 64.f);
    float a = tv * f;
    temb[b][t2] = (t2 < 64) ? cosf(a) : sinf(a);
  }
  __syncthreads();
  if (t2 < 64) {
    float acc = te1_b[t2];
#pragma unroll
    for (int k = 0; k < 128; ++k) acc += temb[b][k] * te1_W[k*64 + t2];
    h1[b][t2] = fmaxf(acc, 0.f);
  }
  __syncthreads();
  if (t2 < 64) {
    float acc = te2_b[t2];
#pragma unroll
    for (int k = 0; k < 64; ++k) acc += h1[b][k] * te2_W[k*64 + t2];
    rt[b][t2] = fmaxf(acc, 0.f);     // relu(te)
  }
  __syncthreads();
  if (t2 < 128) {
#pragma unroll
    for (int i = 0; i < LL; ++i) {
      float acc = tl_b[i*128 + t2];
#pragma unroll
      for (int k = 0; k < 64; ++k) acc += rt[b][k] * tl_W[(i*64 + k)*128 + t2];
      tproj[(i*BB + b)*128 + t2] = acc;
    }
  }
}

// ---------------- node pos-embed + node_W GEMM -> x (512 x 128) ----------------
__global__ __launch_bounds__(256) void k_node_embed(
    const float* __restrict__ coords, const float* __restrict__ W,
    const float* __restrict__ bias, float* __restrict__ x_out) {
  __shared__ float at[128*LDS_STR];
  int tid = threadIdx.x;
  int row = tid >> 2, part = tid & 3;
  int R = blockIdx.x*64 + row;
  float cy = coords[R*2 + 0], cx = coords[R*2 + 1];
#pragma unroll
  for (int q = 0; q < 32; ++q) {
    int c = part*32 + q;
    int k = (c < 64) ? c : c - 64;
    float v = (c < 64) ? cy : cx;
    int m = k >> 1;
    float inv = __expf(-LOG1E4 * (float)m / 32.f);
    float a = v * TWO_PI * inv;
    at[c*LDS_STR + row] = (k & 1) ? __cosf(a) : __sinf(a);
  }
  __syncthreads();
  int tx = tid & 31, ty = tid >> 5;
  float acc[8][4] = {};
  TILE_GEMM(at, W, acc);
  float4 bb4 = *reinterpret_cast<const float4*>(bias + tx*4);
#pragma unroll
  for (int r = 0; r < 8; ++r) {
    int R2 = blockIdx.x*64 + ty*8 + r;
    float4 o = {acc[r][0]+bb4.x, acc[r][1]+bb4.y, acc[r][2]+bb4.z, acc[r][3]+bb4.w};
    *reinterpret_cast<float4*>(x_out + (size_t)R2*128 + tx*4) = o;
  }
}

// ------- edge_W^T bf16 prep for MFMA edge embed: WTE[n][k] -------
__global__ __launch_bounds__(256) void k_wprep_e(
    const float* __restrict__ EW, u16* __restrict__ WTE) {
  int idx = blockIdx.x*256 + threadIdx.x;    // 0..16383
  int n = idx >> 7, k = idx & 127;
  WTE[n*128 + k] = f2bf(EW[(size_t)k*128 + n]);
}

// ------- MFMA edge pos-embed: e = posembed(adj) @ edge_W + edge_b -------
__global__ __launch_bounds__(256, 3) void k_edge_embed2(
    const float* __restrict__ adj, const u16* __restrict__ WTE,
    const float* __restrict__ bias, float* __restrict__ e_out) {
  __shared__ __align__(16) u16 Abuf[64*128];    // 16 KB pos-embed bf16
  __shared__ __align__(16) u16 Wbuf[128*128];   // 32 KB edge_W^T

  const int tid = threadIdx.x;
  const int blk = blockIdx.x;
  const int w  = tid >> 6;
  const int l  = tid & 63;
  const int lg = l >> 4;
  const int ln = l & 15;

  {
    const int r = tid >> 1, h = tid & 1;
    const int r7 = r & 7;
    const u16* src = WTE + r*128;
    u16* dst = Wbuf + r*128;
#pragma unroll
    for (int q = 0; q < 8; ++q) {
      int c = h*8 + q;
      short8 v = *reinterpret_cast<const short8*>(src + c*8);
      *reinterpret_cast<short8*>(dst + ((c ^ r7) << 3)) = v;
    }
  }
  {
    const int r = tid >> 2;          // 0..63
    const int p = tid & 3;
    const float v = adj[(size_t)blk*64 + r];
    const int r7 = r & 7;
    u16* arow = Abuf + r*128;
#pragma unroll
    for (int q = 0; q < 4; ++q) {
      u16 h8[8];
#pragma unroll
      for (int j = 0; j < 8; ++j) {
        int k = (p*4 + q)*8 + j;     // column 0..127
        int m = k >> 1;
        float inv = __expf(-LOG1E4 * (float)m / 64.f);
        float a = v * inv;
        h8[j] = f2bf((k & 1) ? __cosf(a) : __sinf(a));
      }
      int pc = (p*4 + q) ^ r7;
      *reinterpret_cast<ushort8*>(arow + pc*8) = *reinterpret_cast<ushort8*>(h8);
    }
  }
  __syncthreads();

  f32x4 acc[8];
#pragma unroll
  for (int nt = 0; nt < 8; ++nt) {
    const float bv = bias[nt*16 + ln];
#pragma unroll
    for (int rg = 0; rg < 4; ++rg) acc[nt][rg] = bv;
  }
  {
    const u16* arow = Abuf + (w*16 + ln)*128;
    const int r7 = ln & 7;
#pragma unroll
    for (int ks = 0; ks < 4; ++ks) {
      short8 a = *reinterpret_cast<const short8*>(arow + (((ks*4 + lg) ^ r7) << 3));
#pragma unroll
      for (int nt = 0; nt < 8; ++nt) {
        short8 bw = *reinterpret_cast<const short8*>(
            Wbuf + (nt*16 + ln)*128 + (((ks*4 + lg) ^ (ln & 7)) << 3));
        acc[nt] = __builtin_amdgcn_mfma_f32_16x16x32_bf16(a, bw, acc[nt], 0, 0, 0);
      }
    }
  }
#pragma unroll
  for (int nt = 0; nt < 8; ++nt)
#pragma unroll
    for (int rg = 0; rg < 4; ++rg)
      e_out[((size_t)blk*64 + w*16 + lg*4 + rg)*128 + nt*16 + ln] = acc[nt][rg];
}

// ---------------- per-layer node linears: Uh,Vh,Ax,Bx (512 rows) ----------------
__global__ __launch_bounds__(128) void k_node4(
    const float* __restrict__ x,
    const float* __restrict__ UW, const float* __restrict__ Ub,
    const float* __restrict__ VW, const float* __restrict__ Vb,
    const float* __restrict__ AW, const float* __restrict__ Ab,
    const float* __restrict__ BW, const float* __restrict__ Bb,
    float* __restrict__ Uh, float* __restrict__ Vh,
    float* __restrict__ Axo, float* __restrict__ Bxo) {
  __shared__ float xr[128];
  int R = blockIdx.x, d = threadIdx.x;
  xr[d] = x[(size_t)R*128 + d];
  __syncthreads();
  float au = Ub[d], av = Vb[d], aa = Ab[d], ab = Bb[d];
  for (int k = 0; k < 128; ++k) {
    float xv = xr[k];
    au += xv * UW[k*128 + d];
    av += xv * VW[k*128 + d];
    aa += xv * AW[k*128 + d];
    ab += xv * BW[k*128 + d];
  }
  Uh[(size_t)R*128 + d] = au;
  Vh[(size_t)R*128 + d] = av;
  Axo[(size_t)R*128 + d] = aa;
  Bxo[(size_t)R*128 + d] = ab;
}

// ===== fused x-update + next-layer node linears (per node) =====
__global__ __launch_bounds__(128) void k_xnode(
    const float* __restrict__ aggP,
    const float* __restrict__ lnh_s, const float* __restrict__ lnh_b,
    float* __restrict__ x,
    const float* __restrict__ UW, const float* __restrict__ Ub,
    const float* __restrict__ VW, const float* __restrict__ Vb,
    const float* __restrict__ AW, const float* __restrict__ Ab,
    const float* __restrict__ BW, const float* __restrict__ Bb,
    float* __restrict__ Uh, float* __restrict__ Vh,
    float* __restrict__ Axo, float* __restrict__ Bxo) {
  __shared__ float xr[128];
  __shared__ float red[4];
  int bi = blockIdx.x, d = threadIdx.x;
  float u = Uh[(size_t)bi*128 + d];
#pragma unroll
  for (int st = 0; st < 16; ++st) u += aggP[((size_t)bi*16 + st)*128 + d];
  float s = u, s2 = u*u;
#pragma unroll
  for (int m = 1; m <= 32; m <<= 1) { s += __shfl_xor(s, m); s2 += __shfl_xor(s2, m); }
  int wid = d >> 6;
  if ((d & 63) == 0) { red[wid] = s; red[2 + wid] = s2; }
  __syncthreads();
  s = red[0] + red[1];  s2 = red[2] + red[3];
  float mean = s * (1.f/128.f);
  float rs = rsqrtf(s2 * (1.f/128.f) - mean*mean + 1e-5f);
  float xv = x[(size_t)bi*128 + d] + fmaxf((u - mean)*rs*lnh_s[d] + lnh_b[d], 0.f);
  x[(size_t)bi*128 + d] = xv;
  xr[d] = xv;
  __syncthreads();
  float au = Ub[d], av = Vb[d], aa = Ab[d], ab = Bb[d];
  for (int k = 0; k < 128; ++k) {
    float xk = xr[k];
    au += xk * UW[k*128 + d];
    av += xk * VW[k*128 + d];
    aa += xk * AW[k*128 + d];
    ab += xk * BW[k*128 + d];
  }
  Uh[(size_t)bi*128 + d] = au;
  Vh[(size_t)bi*128 + d] = av;
  Axo[(size_t)bi*128 + d] = aa;
  Bxo[(size_t)bi*128 + d] = ab;
}

// ---------------- weight prep: bf16 transposed copies WT[n][k] ----------------
__global__ __launch_bounds__(256) void k_wprep(
    const float* __restrict__ CW, const float* __restrict__ PW,
    u16* __restrict__ WTC, u16* __restrict__ WTP) {
  int idx = blockIdx.x*256 + threadIdx.x;    // 0..131071
  int m = idx >> 14;                          // 0..7 (layer*2 + type)
  int r = idx & 16383;
  int layer = m >> 1;
  int n = r >> 7, k = r & 127;
  if ((m & 1) == 0)
    WTC[layer*16384 + n*128 + k] = f2bf(CW[(size_t)layer*16384 + k*128 + n]);
  else
    WTP[layer*16384 + n*128 + k] = f2bf(PW[(size_t)layer*16384 + k*128 + n]);
}

// ===== fused per-layer MFMA kernel: 512-thr / 128-row blocks (r17/r20 EXACT) =====
__global__ __launch_bounds__(512, 2) void k_layer(
    float* __restrict__ e,
    const u16* __restrict__ WTC, const u16* __restrict__ WTP,
    const float* __restrict__ Cb, const float* __restrict__ Ax,
    const float* __restrict__ Bx, const float* __restrict__ Vh,
    const float* __restrict__ lnes_g, const float* __restrict__ lneb_g,
    const float* __restrict__ tp_g,
    const float* __restrict__ plos_g, const float* __restrict__ plobl_g,
    const float* __restrict__ plob_g,
    float* __restrict__ aggP) {

  __shared__ __align__(16) u16 Abuf[128*128];   // 32 KB (e, then sv)
  __shared__ __align__(16) u16 Wbuf[128*128];   // 32 KB (WTC, then WTP)

  const int tid = threadIdx.x;
  const int blk0 = blockIdx.x;
  const int blk = ((blk0 & 7) << 7) | (blk0 >> 3);   // XCD swizzle (1024%8==0)
  const int bi  = blk >> 1;          // b*256 + i
  const int b   = bi >> 8;
  const int jh  = blk & 1;           // 128-row half
  const size_t rbase = (size_t)bi*256 + jh*128;

  const int w  = tid >> 6;           // 0..7
  const int l  = tid & 63;
  const int lg = l >> 4;             // 0..3
  const int ln = l & 15;             // 0..15

  {
    const int r = tid >> 2;          // 0..127
    const int p = tid & 3;
    const float* src = e + (rbase + r)*128 + p*32;
    const int r7 = r & 7;
    u16* arow = Abuf + r*128;
#pragma unroll
    for (int q = 0; q < 4; ++q) {
      float4 f0 = *reinterpret_cast<const float4*>(src + q*8);
      float4 f1 = *reinterpret_cast<const float4*>(src + q*8 + 4);
      int pc = (p*4 + q) ^ r7;
      ushort8 h = {f2bf(f0.x),f2bf(f0.y),f2bf(f0.z),f2bf(f0.w),
                   f2bf(f1.x),f2bf(f1.y),f2bf(f1.z),f2bf(f1.w)};
      *reinterpret_cast<ushort8*>(arow + pc*8) = h;
    }
  }
  {
    const int r = tid >> 2;          // 0..127
    const int h = tid & 3;
    const int r7 = r & 7;
    const u16* src = WTC + r*128;
    u16* dst = Wbuf + r*128;
#pragma unroll
    for (int q = 0; q < 4; ++q) {
      int c = h*4 + q;               // 16B chunk index 0..15
      short8 v = *reinterpret_cast<const short8*>(src + c*8);
      *reinterpret_cast<short8*>(dst + ((c ^ r7) << 3)) = v;
    }
  }
  __syncthreads();   // barrier 1

  const int lrow0 = w*16 + lg*4;
  const int jrow0 = jh*128 + lrow0;

  f32x4 acc[8];
#pragma unroll
  for (int nt = 0; nt < 8; ++nt) {
    const int c = nt*16 + ln;
    const float cbax = Cb[c] + Ax[(size_t)bi*128 + c];
#pragma unroll
    for (int rg = 0; rg < 4; ++rg)
      acc[nt][rg] = cbax + Bx[((size_t)b*256 + jrow0 + rg)*128 + c];
  }

  {
    const u16* arow = Abuf + (w*16 + ln)*128;
    const int r7 = ln & 7;
#pragma unroll
    for (int ks = 0; ks < 4; ++ks) {
      short8 a = *reinterpret_cast<const short8*>(arow + (((ks*4 + lg) ^ r7) << 3));
#pragma unroll
      for (int nt = 0; nt < 8; ++nt) {
        short8 bw = *reinterpret_cast<const short8*>(
            Wbuf + (nt*16 + ln)*128 + (((ks*4 + lg) ^ (ln & 7)) << 3));
        acc[nt] = __builtin_amdgcn_mfma_f32_16x16x32_bf16(a, bw, acc[nt], 0, 0, 0);
      }
    }
  }

  float av[8] = {0.f,0.f,0.f,0.f,0.f,0.f,0.f,0.f};
  float tp_[8], ls_[8], lb_[8], ps_[8], pl_[8];
#pragma unroll
  for (int nt = 0; nt < 8; ++nt) {
    const int c = nt*16 + ln;
    tp_[nt] = tp_g[b*128 + c];
    ls_[nt] = lnes_g[c];  lb_[nt] = lneb_g[c];
    ps_[nt] = plos_g[c];  pl_[nt] = plobl_g[c];
  }

#pragma unroll
  for (int rg = 0; rg < 4; ++rg) {
    float ss = 0.f, s2 = 0.f;
#pragma unroll
    for (int nt = 0; nt < 8; ++nt) { float g = acc[nt][rg]; ss += g; s2 += g*g; }
    ss += __shfl_xor(ss, 1);  s2 += __shfl_xor(s2, 1);
    ss += __shfl_xor(ss, 2);  s2 += __shfl_xor(s2, 2);
    ss += __shfl_xor(ss, 4);  s2 += __shfl_xor(s2, 4);
    ss += __shfl_xor(ss, 8);  s2 += __shfl_xor(s2, 8);
    const float mean = ss * (1.f/128.f);
    const float rs = rsqrtf(s2 * (1.f/128.f) - mean*mean + 1e-5f);
    const size_t vrow = ((size_t)b*256 + jrow0 + rg)*128;
    float s3 = 0.f, s4 = 0.f;
#pragma unroll
    for (int nt = 0; nt < 8; ++nt) {
      const float g = acc[nt][rg];
      av[nt] += Vh[vrow + nt*16 + ln] * sigmoidf_(g);
      float tv = fmaxf((g - mean)*rs*ls_[nt] + lb_[nt], 0.f) + tp_[nt];
      acc[nt][rg] = tv;
      s3 += tv;  s4 += tv*tv;
    }
    s3 += __shfl_xor(s3, 1);  s4 += __shfl_xor(s4, 1);
    s3 += __shfl_xor(s3, 2);  s4 += __shfl_xor(s4, 2);
    s3 += __shfl_xor(s3, 4);  s4 += __shfl_xor(s4, 4);
    s3 += __shfl_xor(s3, 8);  s4 += __shfl_xor(s4, 8);
    const float mean2 = s3 * (1.f/128.f);
    const float rs2 = rsqrtf(s4 * (1.f/128.f) - mean2*mean2 + 1e-5f);
    const int rr = lrow0 + rg;
    const int rr7 = rr & 7;
#pragma unroll
    for (int nt = 0; nt < 8; ++nt) {
      float vv = (acc[nt][rg] - mean2)*rs2*ps_[nt] + pl_[nt];
      vv = vv * sigmoidf_(vv);
      const int cc = nt*16 + ln;
      const int pc = (cc >> 3) ^ rr7;
      Abuf[rr*128 + pc*8 + (cc & 7)] = f2bf(vv);
    }
  }

  __syncthreads();
  {
    const int r = tid >> 2;
    const int h = tid & 3;
    const int r7 = r & 7;
    const u16* src = WTP + r*128;
    u16* dst = Wbuf + r*128;
#pragma unroll
    for (int q = 0; q < 4; ++q) {
      int c = h*4 + q;
      short8 v = *reinterpret_cast<const short8*>(src + c*8);
      *reinterpret_cast<short8*>(dst + ((c ^ r7) << 3)) = v;
    }
  }
  __syncthreads();

  f32x4 acc2[8];
#pragma unroll
  for (int nt = 0; nt < 8; ++nt) acc2[nt] = (f32x4)(0.f);
  {
    const u16* arow = Abuf + (w*16 + ln)*128;
    const int r7 = ln & 7;
#pragma unroll
    for (int ks = 0; ks < 4; ++ks) {
      short8 a = *reinterpret_cast<const short8*>(arow + (((ks*4 + lg) ^ r7) << 3));
#pragma unroll
      for (int nt = 0; nt < 8; ++nt) {
        short8 bw = *reinterpret_cast<const short8*>(
            Wbuf + (nt*16 + ln)*128 + (((ks*4 + lg) ^ (ln & 7)) << 3));
        acc2[nt] = __builtin_amdgcn_mfma_f32_16x16x32_bf16(a, bw, acc2[nt], 0, 0, 0);
      }
    }
  }

#pragma unroll
  for (int nt = 0; nt < 8; ++nt) {
    const float pbv = plob_g[nt*16 + ln];
#pragma unroll
    for (int rg = 0; rg < 4; ++rg) {
      float* ep = e + (rbase + lrow0 + rg)*128 + nt*16 + ln;
      *ep = *ep + acc2[nt][rg] + pbv;
    }
  }

#pragma unroll
  for (int nt = 0; nt < 8; ++nt) {
    float v = av[nt];
    v += __shfl_xor(v, 16);
    v += __shfl_xor(v, 32);
    av[nt] = v;
  }
  if (lg == 0) {
#pragma unroll
    for (int nt = 0; nt < 8; ++nt)
      aggP[((size_t)blk*8 + w)*128 + nt*16 + ln] = av[nt];
  }
}

// ===== k_layer_s: identical to k_layer + GN-stats accumulation (layer 3) =====
// Stats logic is r16's proven-correct path (r16 passed at 2.197e-3).
__global__ __launch_bounds__(512, 2) void k_layer_s(
    float* __restrict__ e,
    const u16* __restrict__ WTC, const u16* __restrict__ WTP,
    const float* __restrict__ Cb, const float* __restrict__ Ax,
    const float* __restrict__ Bx, const float* __restrict__ Vh,
    const float* __restrict__ lnes_g, const float* __restrict__ lneb_g,
    const float* __restrict__ tp_g,
    const float* __restrict__ plos_g, const float* __restrict__ plobl_g,
    const float* __restrict__ plob_g,
    float* __restrict__ aggP, float* __restrict__ sraw) {

  __shared__ __align__(16) u16 Abuf[128*128];
  __shared__ __align__(16) u16 Wbuf[128*128];
  __shared__ float sgrp[64];

  const int tid = threadIdx.x;
  const int blk0 = blockIdx.x;
  const int blk = ((blk0 & 7) << 7) | (blk0 >> 3);
  const int bi  = blk >> 1;
  const int b   = bi >> 8;
  const int jh  = blk & 1;
  const size_t rbase = (size_t)bi*256 + jh*128;

  const int w  = tid >> 6;
  const int l  = tid & 63;
  const int lg = l >> 4;
  const int ln = l & 15;

  {
    const int r = tid >> 2;
    const int p = tid & 3;
    const float* src = e + (rbase + r)*128 + p*32;
    const int r7 = r & 7;
    u16* arow = Abuf + r*128;
#pragma unroll
    for (int q = 0; q < 4; ++q) {
      float4 f0 = *reinterpret_cast<const float4*>(src + q*8);
      float4 f1 = *reinterpret_cast<const float4*>(src + q*8 + 4);
      int pc = (p*4 + q) ^ r7;
      ushort8 h = {f2bf(f0.x),f2bf(f0.y),f2bf(f0.z),f2bf(f0.w),
                   f2bf(f1.x),f2bf(f1.y),f2bf(f1.z),f2bf(f1.w)};
      *reinterpret_cast<ushort8*>(arow + pc*8) = h;
    }
  }
  {
    const int r = tid >> 2;
    const int h = tid & 3;
    const int r7 = r & 7;
    const u16* src = WTC + r*128;
    u16* dst = Wbuf + r*128;
#pragma unroll
    for (int q = 0; q < 4; ++q) {
      int c = h*4 + q;
      short8 v = *reinterpret_cast<const short8*>(src + c*8);
      *reinterpret_cast<short8*>(dst + ((c ^ r7) << 3)) = v;
    }
  }
  if (tid < 64) sgrp[tid] = 0.f;
  __syncthreads();

  const int lrow0 = w*16 + lg*4;
  const int jrow0 = jh*128 + lrow0;

  f32x4 acc[8];
#pragma unroll
  for (int nt = 0; nt < 8; ++nt) {
    const int c = nt*16 + ln;
    const float cbax = Cb[c] + Ax[(size_t)bi*128 + c];
#pragma unroll
    for (int rg = 0; rg < 4; ++rg)
      acc[nt][rg] = cbax + Bx[((size_t)b*256 + jrow0 + rg)*128 + c];
  }

  {
    const u16* arow = Abuf + (w*16 + ln)*128;
    const int r7 = ln & 7;
#pragma unroll
    for (int ks = 0; ks < 4; ++ks) {
      short8 a = *reinterpret_cast<const short8*>(arow + (((ks*4 + lg) ^ r7) << 3));
#pragma unroll
      for (int nt = 0; nt < 8; ++nt) {
        short8 bw = *reinterpret_cast<const short8*>(
            Wbuf + (nt*16 + ln)*128 + (((ks*4 + lg) ^ (ln & 7)) << 3));
        acc[nt] = __builtin_amdgcn_mfma_f32_16x16x32_bf16(a, bw, acc[nt], 0, 0, 0);
      }
    }
  }

  float av[8] = {0.f,0.f,0.f,0.f,0.f,0.f,0.f,0.f};
  float tp_[8], ls_[8], lb_[8], ps_[8], pl_[8];
#pragma unroll
  for (int nt = 0; nt < 8; ++nt) {
    const int c = nt*16 + ln;
    tp_[nt] = tp_g[b*128 + c];
    ls_[nt] = lnes_g[c];  lb_[nt] = lneb_g[c];
    ps_[nt] = plos_g[c];  pl_[nt] = plobl_g[c];
  }

#pragma unroll
  for (int rg = 0; rg < 4; ++rg) {
    float ss = 0.f, s2 = 0.f;
#pragma unroll
    for (int nt = 0; nt < 8; ++nt) { float g = acc[nt][rg]; ss += g; s2 += g*g; }
    ss += __shfl_xor(ss, 1);  s2 += __shfl_xor(s2, 1);
    ss += __shfl_xor(ss, 2);  s2 += __shfl_xor(s2, 2);
    ss += __shfl_xor(ss, 4);  s2 += __shfl_xor(s2, 4);
    ss += __shfl_xor(ss, 8);  s2 += __shfl_xor(s2, 8);
    const float mean = ss * (1.f/128.f);
    const float rs = rsqrtf(s2 * (1.f/128.f) - mean*mean + 1e-5f);
    const size_t vrow = ((size_t)b*256 + jrow0 + rg)*128;
    float s3 = 0.f, s4 = 0.f;
#pragma unroll
    for (int nt = 0; nt < 8; ++nt) {
      const float g = acc[nt][rg];
      av[nt] += Vh[vrow + nt*16 + ln] * sigmoidf_(g);
      float tv = fmaxf((g - mean)*rs*ls_[nt] + lb_[nt], 0.f) + tp_[nt];
      acc[nt][rg] = tv;
      s3 += tv;  s4 += tv*tv;
    }
    s3 += __shfl_xor(s3, 1);  s4 += __shfl_xor(s4, 1);
    s3 += __shfl_xor(s3, 2);  s4 += __shfl_xor(s4, 2);
    s3 += __shfl_xor(s3, 4);  s4 += __shfl_xor(s4, 4);
    s3 += __shfl_xor(s3, 8);  s4 += __shfl_xor(s4, 8);
    const float mean2 = s3 * (1.f/128.f);
    const float rs2 = rsqrtf(s4 * (1.f/128.f) - mean2*mean2 + 1e-5f);
    const int rr = lrow0 + rg;
    const int rr7 = rr & 7;
#pragma unroll
    for (int nt = 0; nt < 8; ++nt) {
      float vv = (acc[nt][rg] - mean2)*rs2*ps_[nt] + pl_[nt];
      vv = vv * sigmoidf_(vv);
      const int cc = nt*16 + ln;
      const int pc = (cc >> 3) ^ rr7;
      Abuf[rr*128 + pc*8 + (cc & 7)] = f2bf(vv);
    }
  }

  __syncthreads();
  {
    const int r = tid >> 2;
    const int h = tid & 3;
    const int r7 = r & 7;
    const u16* src = WTP + r*128;
    u16* dst = Wbuf + r*128;
#pragma unroll
    for (int q = 0; q < 4; ++q) {
      int c = h*4 + q;
      short8 v = *reinterpret_cast<const short8*>(src + c*8);
      *reinterpret_cast<short8*>(dst + ((c ^ r7) << 3)) = v;
    }
  }
  __syncthreads();

  f32x4 acc2[8];
#pragma unroll
  for (int nt = 0; nt < 8; ++nt) acc2[nt] = (f32x4)(0.f);
  {
    const u16* arow = Abuf + (w*16 + ln)*128;
    const int r7 = ln & 7;
#pragma unroll
    for (int ks = 0; ks < 4; ++ks) {
      short8 a = *reinterpret_cast<const short8*>(arow + (((ks*4 + lg) ^ r7) << 3));
#pragma unroll
      for (int nt = 0; nt < 8; ++nt) {
        short8 bw = *reinterpret_cast<const short8*>(
            Wbuf + (nt*16 + ln)*128 + (((ks*4 + lg) ^ (ln & 7)) << 3));
        acc2[nt] = __builtin_amdgcn_mfma_f32_16x16x32_bf16(a, bw, acc2[nt], 0, 0, 0);
      }
    }
  }

#pragma unroll
  for (int nt = 0; nt < 8; ++nt) {
    const float pbv = plob_g[nt*16 + ln];
#pragma unroll
    for (int rg = 0; rg < 4; ++rg) {
      float* ep = e + (rbase + lrow0 + rg)*128 + nt*16 + ln;
      float v = *ep + acc2[nt][rg] + pbv;
      *ep = v;
      acc2[nt][rg] = v;              // keep final value for stats
    }
  }

  // ---- GN stats: group g = nt*4 + (ln>>2) (r16-proven) ----
#pragma unroll
  for (int nt = 0; nt < 8; ++nt) {
    float gs = acc2[nt][0] + acc2[nt][1] + acc2[nt][2] + acc2[nt][3];
    float gq = acc2[nt][0]*acc2[nt][0] + acc2[nt][1]*acc2[nt][1]
             + acc2[nt][2]*acc2[nt][2] + acc2[nt][3]*acc2[nt][3];
    gs += __shfl_xor(gs, 1);  gq += __shfl_xor(gq, 1);
    gs += __shfl_xor(gs, 2);  gq += __shfl_xor(gq, 2);
    gs += __shfl_xor(gs, 16); gq += __shfl_xor(gq, 16);
    gs += __shfl_xor(gs, 32); gq += __shfl_xor(gq, 32);
    if ((l & 51) == 0) {             // ln&3==0 && lg==0
      int g = nt*4 + (ln >> 2);
      atomicAdd(&sgrp[g*2],     gs);
      atomicAdd(&sgrp[g*2 + 1], gq);
    }
  }
  __syncthreads();
  if (tid < 64)
    atomicAdd(&sraw[(size_t)b*64 + tid], sgrp[tid]);

#pragma unroll
  for (int nt = 0; nt < 8; ++nt) {
    float v = av[nt];
    v += __shfl_xor(v, 16);
    v += __shfl_xor(v, 32);
    av[nt] = v;
  }
  if (lg == 0) {
#pragma unroll
    for (int nt = 0; nt < 8; ++nt)
      aggP[((size_t)blk*8 + w)*128 + nt*16 + ln] = av[nt];
  }
}

// ---------------- x update: x += relu(LN(Uh + agg)) (final layer only) --------
__global__ __launch_bounds__(128) void k_xupd(
    const float* __restrict__ aggP, const float* __restrict__ Uh,
    const float* __restrict__ lnh_s, const float* __restrict__ lnh_b,
    float* __restrict__ x) {
  int bi = blockIdx.x, d = threadIdx.x;
  float u = Uh[(size_t)bi*128 + d];
#pragma unroll
  for (int st = 0; st < 16; ++st) u += aggP[((size_t)bi*16 + st)*128 + d];
  float s = u, s2 = u*u;
#pragma unroll
  for (int m = 1; m <= 32; m <<= 1) { s += __shfl_xor(s, m); s2 += __shfl_xor(s2, m); }
  __shared__ float red[4];
  int wid = d >> 6;
  if ((d & 63) == 0) { red[wid] = s; red[2 + wid] = s2; }
  __syncthreads();
  s = red[0] + red[1];  s2 = red[2] + red[3];
  float mean = s * (1.f/128.f);
  float rs = rsqrtf(s2 * (1.f/128.f) - mean*mean + 1e-5f);
  x[(size_t)bi*128 + d] += fmaxf((u - mean)*rs*lnh_s[d] + lnh_b[d], 0.f);
}

// ---------------- zero the GN stats accumulators ----------------
__global__ __launch_bounds__(128) void k_zero(float* __restrict__ p) {
  p[threadIdx.x] = 0.f;
}

// ---- final: out = relu(gn(e)) . conv_W + conv_b; gnfin folded in ----
// sraw layout: [b*64 + g*2 + {0,1}] raw sums (from k_layer_s).
__global__ __launch_bounds__(256) void k_out(
    const float* __restrict__ e, const float* __restrict__ sraw,
    const float* __restrict__ gn_s, const float* __restrict__ gn_b,
    const float* __restrict__ convW, const float* __restrict__ convb,
    float* __restrict__ out) {
  __shared__ float st[64];           // [g*2]=mean, [g*2+1]=rs for this block's b
  int tid = threadIdx.x;
  size_t b = ((size_t)blockIdx.x*64) >> 16;   // constant per block
  if (tid < 32) {
    const float cnt = (float)(NN*NN*4);
    float S  = sraw[b*64 + tid*2];
    float S2 = sraw[b*64 + tid*2 + 1];
    float mean = S / cnt;
    float var = S2 / cnt - mean*mean;
    st[tid*2]     = mean;
    st[tid*2 + 1] = rsqrtf(var + 1e-5f);
  }
  __syncthreads();
  int row = tid >> 2, part = tid & 3;
  size_t R = (size_t)blockIdx.x*64 + row;
  float acc = 0.f;
  const float4* er = reinterpret_cast<const float4*>(e + R*128 + part*32);
#pragma unroll
  for (int q = 0; q < 8; ++q) {
    float4 f = er[q];
    float fv[4] = {f.x, f.y, f.z, f.w};
#pragma unroll
    for (int lidx = 0; lidx < 4; ++lidx) {
      int c = part*32 + q*4 + lidx;
      int g = c >> 2;
      float mean = st[g*2 + 0];
      float rs   = st[g*2 + 1];
      float t = (fv[lidx] - mean)*rs*gn_s[c] + gn_b[c];
      acc += fmaxf(t, 0.f) * convW[c];
    }
  }
  acc += __shfl_xor(acc, 1);
  acc += __shfl_xor(acc, 2);
  if (part == 0) out[R] = acc + convb[0];
}

extern "C" void kernel_launch(void* const* d_in, const int* in_sizes, int n_in,
                              void* d_out, int out_size, void* d_ws, size_t ws_size,
                              hipStream_t stream) {
  const float* coords  = (const float*)d_in[0];
  const float* adj_t   = (const float*)d_in[1];
  const float* t       = (const float*)d_in[2];
  const float* node_W  = (const float*)d_in[3];
  const float* node_b  = (const float*)d_in[4];
  const float* edge_W  = (const float*)d_in[5];
  const float* edge_b  = (const float*)d_in[6];
  const float* te1_W   = (const float*)d_in[7];
  const float* te1_b   = (const float*)d_in[8];
  const float* te2_W   = (const float*)d_in[9];
  const float* te2_b   = (const float*)d_in[10];
  const float* A_W     = (const float*)d_in[11];
  const float* A_b     = (const float*)d_in[12];
  const float* B_W     = (const float*)d_in[13];
  const float* B_b     = (const float*)d_in[14];
  const float* C_W     = (const float*)d_in[15];
  const float* C_b     = (const float*)d_in[16];
  const float* U_W     = (const float*)d_in[17];
  const float* U_b     = (const float*)d_in[18];
  const float* V_W     = (const float*)d_in[19];
  const float* V_b     = (const float*)d_in[20];
  const float* lnh_s   = (const float*)d_in[21];
  const float* lnh_b   = (const float*)d_in[22];
  const float* lne_s   = (const float*)d_in[23];
  const float* lne_b   = (const float*)d_in[24];
  const float* tl_W    = (const float*)d_in[25];
  const float* tl_b    = (const float*)d_in[26];
  const float* plo_ln_s= (const float*)d_in[27];
  const float* plo_ln_b= (const float*)d_in[28];
  const float* plo_W   = (const float*)d_in[29];
  const float* plo_b   = (const float*)d_in[30];
  const float* gn_s    = (const float*)d_in[31];
  const float* gn_b    = (const float*)d_in[32];
  const float* conv_W  = (const float*)d_in[33];
  const float* conv_b  = (const float*)d_in[34];

  float* ws    = (float*)d_ws;
  float* e     = ws;                        // 16,777,216 floats
  float* x     = e + (size_t)NROWS*128;
  float* Uh    = x + 65536;
  float* Vh    = Uh + 65536;
  float* Ax    = Vh + 65536;
  float* Bx    = Ax + 65536;
  float* tproj = Bx + 65536;                // 1024
  float* sraw  = tproj + 1024;              // 128 (b*64 + g*2 + {0,1})
  float* aggP  = sraw + 128;                // 1024*8*128 = 1,048,576
  u16*   WTC   = (u16*)(aggP + 1048576);    // 4*16384 u16
  u16*   WTP   = WTC + (size_t)LL*16384;
  u16*   WTE   = WTP + (size_t)LL*16384;    // 16384 u16

  k_zero<<<1, 128, 0, stream>>>(sraw);
  k_wprep<<<512, 256, 0, stream>>>(C_W, plo_W, WTC, WTP);
  k_wprep_e<<<64, 256, 0, stream>>>(edge_W, WTE);
  k_time<<<1, 512, 0, stream>>>(t, te1_W, te1_b, te2_W, te2_b, tl_W, tl_b, tproj);
  k_node_embed<<<8, 256, 0, stream>>>(coords, node_W, node_b, x);
  k_edge_embed2<<<NROWS/64, 256, 0, stream>>>(adj_t, WTE, edge_b, e);

  for (int i = 0; i < LL; ++i) {
    if (i == 0) {
      k_node4<<<BB*NN, 128, 0, stream>>>(x,
          U_W, U_b, V_W, V_b, A_W, A_b, B_W, B_b,
          Uh, Vh, Ax, Bx);
    } else {
      k_xnode<<<BB*NN, 128, 0, stream>>>(aggP,
          lnh_s + (i-1)*128, lnh_b + (i-1)*128, x,
          U_W + (size_t)i*16384, U_b + i*128,
          V_W + (size_t)i*16384, V_b + i*128,
          A_W + (size_t)i*16384, A_b + i*128,
          B_W + (size_t)i*16384, B_b + i*128,
          Uh, Vh, Ax, Bx);
    }
    if (i < LL-1) {
      k_layer<<<NROWS/128, 512, 0, stream>>>(e,
          WTC + (size_t)i*16384, WTP + (size_t)i*16384,
          C_b + i*128, Ax, Bx, Vh,
          lne_s + i*128, lne_b + i*128,
          tproj + i*BB*128,
          plo_ln_s + i*128, plo_ln_b + i*128, plo_b + i*128,
          aggP);
    } else {
      k_layer_s<<<NROWS/128, 512, 0, stream>>>(e,
          WTC + (size_t)i*16384, WTP + (size_t)i*16384,
          C_b + i*128, Ax, Bx, Vh,
          lne_s + i*128, lne_b + i*128,
          tproj + i*BB*128,
          plo_ln_s + i*128, plo_ln_b + i*128, plo_b + i*128,
          aggP, sraw);
    }
  }
  k_xupd<<<BB*NN, 128, 0, stream>>>(aggP, Uh, lnh_s + 3*128, lnh_b + 3*128, x);

  k_out<<<NROWS/64, 256, 0, stream>>>(e, sraw, gn_s, gn_b, conv_W, conv_b,
                                      (float*)d_out);
}

// Round 22
// 392.382 us; speedup vs baseline: 1.0920x; 1.0106x over previous
//
#include <hip/hip_runtime.h>
#include <hip/hip_bf16.h>

typedef unsigned short u16;
typedef __attribute__((ext_vector_type(8))) short short8;
typedef __attribute__((ext_vector_type(8))) unsigned short ushort8;
typedef __attribute__((ext_vector_type(4))) float f32x4;

#define BB 2
#define NN 256
#define DD 128
#define TDD 64
#define LL 4
#define NGROUP 32
#define NROWS (BB*NN*NN)      // 131072 edge rows
#define LDS_STR 68            // padded LDS stride for fp32 embed kernels

#define LOG1E4 9.210340371976184f
#define TWO_PI 6.283185307179586f

// ---------------- fp32 tile GEMM (node embed kernel only) ----------------
#define TILE_GEMM(AT, WPTR, ACC) do {                                          \
  _Pragma("unroll 4")                                                          \
  for (int k = 0; k < 128; ++k) {                                              \
    const float4 w4 = *reinterpret_cast<const float4*>((WPTR) + k*128 + tx*4); \
    const float4 a0 = *reinterpret_cast<const float4*>(&(AT)[k*LDS_STR + ty*8]);     \
    const float4 a1 = *reinterpret_cast<const float4*>(&(AT)[k*LDS_STR + ty*8 + 4]); \
    const float av[8] = {a0.x,a0.y,a0.z,a0.w,a1.x,a1.y,a1.z,a1.w};             \
    const float wv[4] = {w4.x,w4.y,w4.z,w4.w};                                 \
    _Pragma("unroll") for (int r = 0; r < 8; ++r)                              \
      _Pragma("unroll") for (int c = 0; c < 4; ++c)                            \
        ACC[r][c] += av[r]*wv[c];                                              \
  }                                                                            \
} while (0)

__device__ __forceinline__ float sigmoidf_(float x) {
  return 1.f / (1.f + __expf(-x));
}

// round-to-nearest-even f32 -> bf16 bits (proven r3-r21)
__device__ __forceinline__ u16 f2bf(float f) {
  union { float f; unsigned int u; } c; c.f = f;
  unsigned int r = (c.u + 0x7FFFu + ((c.u >> 16) & 1u)) >> 16;
  return (u16)r;
}

// ---- time embedding pipeline -> tproj[L][B][D] (parallel over b, unrolled) ----
__global__ __launch_bounds__(512) void k_time(
    const float* __restrict__ t,
    const float* __restrict__ te1_W, const float* __restrict__ te1_b,
    const float* __restrict__ te2_W, const float* __restrict__ te2_b,
    const float* __restrict__ tl_W,  const float* __restrict__ tl_b,
    float* __restrict__ tproj) {
  __shared__ float temb[BB][128], h1[BB][64], rt[BB][64];
  const int tid = threadIdx.x;
  const int b  = tid >> 8;           // 0..1
  const int t2 = tid & 255;          // 0..255 within batch group
  const float tv = t[b];
  if (t2 < 128) {
    int j = t2 & 63;
    float f = expf(-LOG1E4 * (float)j / 64.f);
    float a = tv * f;
    temb[b][t2] = (t2 < 64) ? cosf(a) : sinf(a);
  }
  __syncthreads();
  if (t2 < 64) {
    float acc = te1_b[t2];
#pragma unroll
    for (int k = 0; k < 128; ++k) acc += temb[b][k] * te1_W[k*64 + t2];
    h1[b][t2] = fmaxf(acc, 0.f);
  }
  __syncthreads();
  if (t2 < 64) {
    float acc = te2_b[t2];
#pragma unroll
    for (int k = 0; k < 64; ++k) acc += h1[b][k] * te2_W[k*64 + t2];
    rt[b][t2] = fmaxf(acc, 0.f);     // relu(te)
  }
  __syncthreads();
  if (t2 < 128) {
#pragma unroll
    for (int i = 0; i < LL; ++i) {
      float acc = tl_b[i*128 + t2];
#pragma unroll
      for (int k = 0; k < 64; ++k) acc += rt[b][k] * tl_W[(i*64 + k)*128 + t2];
      tproj[(i*BB + b)*128 + t2] = acc;
    }
  }
}

// ---------------- node pos-embed + node_W GEMM -> x (512 x 128) ----------------
__global__ __launch_bounds__(256) void k_node_embed(
    const float* __restrict__ coords, const float* __restrict__ W,
    const float* __restrict__ bias, float* __restrict__ x_out) {
  __shared__ float at[128*LDS_STR];
  int tid = threadIdx.x;
  int row = tid >> 2, part = tid & 3;
  int R = blockIdx.x*64 + row;
  float cy = coords[R*2 + 0], cx = coords[R*2 + 1];
#pragma unroll
  for (int q = 0; q < 32; ++q) {
    int c = part*32 + q;
    int k = (c < 64) ? c : c - 64;
    float v = (c < 64) ? cy : cx;
    int m = k >> 1;
    float inv = __expf(-LOG1E4 * (float)m / 32.f);
    float a = v * TWO_PI * inv;
    at[c*LDS_STR + row] = (k & 1) ? __cosf(a) : __sinf(a);
  }
  __syncthreads();
  int tx = tid & 31, ty = tid >> 5;
  float acc[8][4] = {};
  TILE_GEMM(at, W, acc);
  float4 bb4 = *reinterpret_cast<const float4*>(bias + tx*4);
#pragma unroll
  for (int r = 0; r < 8; ++r) {
    int R2 = blockIdx.x*64 + ty*8 + r;
    float4 o = {acc[r][0]+bb4.x, acc[r][1]+bb4.y, acc[r][2]+bb4.z, acc[r][3]+bb4.w};
    *reinterpret_cast<float4*>(x_out + (size_t)R2*128 + tx*4) = o;
  }
}

// ------- MFMA edge pos-embed: e = posembed(adj) @ edge_W + edge_b -------
__global__ __launch_bounds__(256, 3) void k_edge_embed2(
    const float* __restrict__ adj, const u16* __restrict__ WTE,
    const float* __restrict__ bias, float* __restrict__ e_out) {
  __shared__ __align__(16) u16 Abuf[64*128];    // 16 KB pos-embed bf16
  __shared__ __align__(16) u16 Wbuf[128*128];   // 32 KB edge_W^T

  const int tid = threadIdx.x;
  const int blk = blockIdx.x;
  const int w  = tid >> 6;
  const int l  = tid & 63;
  const int lg = l >> 4;
  const int ln = l & 15;

  {
    const int r = tid >> 1, h = tid & 1;
    const int r7 = r & 7;
    const u16* src = WTE + r*128;
    u16* dst = Wbuf + r*128;
#pragma unroll
    for (int q = 0; q < 8; ++q) {
      int c = h*8 + q;
      short8 v = *reinterpret_cast<const short8*>(src + c*8);
      *reinterpret_cast<short8*>(dst + ((c ^ r7) << 3)) = v;
    }
  }
  {
    const int r = tid >> 2;          // 0..63
    const int p = tid & 3;
    const float v = adj[(size_t)blk*64 + r];
    const int r7 = r & 7;
    u16* arow = Abuf + r*128;
#pragma unroll
    for (int q = 0; q < 4; ++q) {
      u16 h8[8];
#pragma unroll
      for (int j = 0; j < 8; ++j) {
        int k = (p*4 + q)*8 + j;     // column 0..127
        int m = k >> 1;
        float inv = __expf(-LOG1E4 * (float)m / 64.f);
        float a = v * inv;
        h8[j] = f2bf((k & 1) ? __cosf(a) : __sinf(a));
      }
      int pc = (p*4 + q) ^ r7;
      *reinterpret_cast<ushort8*>(arow + pc*8) = *reinterpret_cast<ushort8*>(h8);
    }
  }
  __syncthreads();

  f32x4 acc[8];
#pragma unroll
  for (int nt = 0; nt < 8; ++nt) {
    const float bv = bias[nt*16 + ln];
#pragma unroll
    for (int rg = 0; rg < 4; ++rg) acc[nt][rg] = bv;
  }
  {
    const u16* arow = Abuf + (w*16 + ln)*128;
    const int r7 = ln & 7;
#pragma unroll
    for (int ks = 0; ks < 4; ++ks) {
      short8 a = *reinterpret_cast<const short8*>(arow + (((ks*4 + lg) ^ r7) << 3));
#pragma unroll
      for (int nt = 0; nt < 8; ++nt) {
        short8 bw = *reinterpret_cast<const short8*>(
            Wbuf + (nt*16 + ln)*128 + (((ks*4 + lg) ^ (ln & 7)) << 3));
        acc[nt] = __builtin_amdgcn_mfma_f32_16x16x32_bf16(a, bw, acc[nt], 0, 0, 0);
      }
    }
  }
#pragma unroll
  for (int nt = 0; nt < 8; ++nt)
#pragma unroll
    for (int rg = 0; rg < 4; ++rg)
      e_out[((size_t)blk*64 + w*16 + lg*4 + rg)*128 + nt*16 + ln] = acc[nt][rg];
}

// ---------------- per-layer node linears: Uh,Vh,Ax,Bx (512 rows) ----------------
__global__ __launch_bounds__(128) void k_node4(
    const float* __restrict__ x,
    const float* __restrict__ UW, const float* __restrict__ Ub,
    const float* __restrict__ VW, const float* __restrict__ Vb,
    const float* __restrict__ AW, const float* __restrict__ Ab,
    const float* __restrict__ BW, const float* __restrict__ Bb,
    float* __restrict__ Uh, float* __restrict__ Vh,
    float* __restrict__ Axo, float* __restrict__ Bxo) {
  __shared__ float xr[128];
  int R = blockIdx.x, d = threadIdx.x;
  xr[d] = x[(size_t)R*128 + d];
  __syncthreads();
  float au = Ub[d], av = Vb[d], aa = Ab[d], ab = Bb[d];
  for (int k = 0; k < 128; ++k) {
    float xv = xr[k];
    au += xv * UW[k*128 + d];
    av += xv * VW[k*128 + d];
    aa += xv * AW[k*128 + d];
    ab += xv * BW[k*128 + d];
  }
  Uh[(size_t)R*128 + d] = au;
  Vh[(size_t)R*128 + d] = av;
  Axo[(size_t)R*128 + d] = aa;
  Bxo[(size_t)R*128 + d] = ab;
}

// ===== fused x-update + next-layer node linears (per node) =====
__global__ __launch_bounds__(128) void k_xnode(
    const float* __restrict__ aggP,
    const float* __restrict__ lnh_s, const float* __restrict__ lnh_b,
    float* __restrict__ x,
    const float* __restrict__ UW, const float* __restrict__ Ub,
    const float* __restrict__ VW, const float* __restrict__ Vb,
    const float* __restrict__ AW, const float* __restrict__ Ab,
    const float* __restrict__ BW, const float* __restrict__ Bb,
    float* __restrict__ Uh, float* __restrict__ Vh,
    float* __restrict__ Axo, float* __restrict__ Bxo) {
  __shared__ float xr[128];
  __shared__ float red[4];
  int bi = blockIdx.x, d = threadIdx.x;
  float u = Uh[(size_t)bi*128 + d];
#pragma unroll
  for (int st = 0; st < 16; ++st) u += aggP[((size_t)bi*16 + st)*128 + d];
  float s = u, s2 = u*u;
#pragma unroll
  for (int m = 1; m <= 32; m <<= 1) { s += __shfl_xor(s, m); s2 += __shfl_xor(s2, m); }
  int wid = d >> 6;
  if ((d & 63) == 0) { red[wid] = s; red[2 + wid] = s2; }
  __syncthreads();
  s = red[0] + red[1];  s2 = red[2] + red[3];
  float mean = s * (1.f/128.f);
  float rs = rsqrtf(s2 * (1.f/128.f) - mean*mean + 1e-5f);
  float xv = x[(size_t)bi*128 + d] + fmaxf((u - mean)*rs*lnh_s[d] + lnh_b[d], 0.f);
  x[(size_t)bi*128 + d] = xv;
  xr[d] = xv;
  __syncthreads();
  float au = Ub[d], av = Vb[d], aa = Ab[d], ab = Bb[d];
  for (int k = 0; k < 128; ++k) {
    float xk = xr[k];
    au += xk * UW[k*128 + d];
    av += xk * VW[k*128 + d];
    aa += xk * AW[k*128 + d];
    ab += xk * BW[k*128 + d];
  }
  Uh[(size_t)bi*128 + d] = au;
  Vh[(size_t)bi*128 + d] = av;
  Axo[(size_t)bi*128 + d] = aa;
  Bxo[(size_t)bi*128 + d] = ab;
}

// ---- weight prep: bf16 transposed copies WT[n][k]; blocks >=512 do WTE + sraw zero ----
__global__ __launch_bounds__(256) void k_wprep(
    const float* __restrict__ CW, const float* __restrict__ PW,
    const float* __restrict__ EW,
    u16* __restrict__ WTC, u16* __restrict__ WTP, u16* __restrict__ WTE,
    float* __restrict__ sraw) {
  if (blockIdx.x < 512) {
    int idx = blockIdx.x*256 + threadIdx.x;  // 0..131071
    int m = idx >> 14;                        // 0..7 (layer*2 + type)
    int r = idx & 16383;
    int layer = m >> 1;
    int n = r >> 7, k = r & 127;
    if ((m & 1) == 0)
      WTC[layer*16384 + n*128 + k] = f2bf(CW[(size_t)layer*16384 + k*128 + n]);
    else
      WTP[layer*16384 + n*128 + k] = f2bf(PW[(size_t)layer*16384 + k*128 + n]);
  } else {
    int r = (blockIdx.x - 512)*256 + threadIdx.x;   // 0..16383
    int n = r >> 7, k = r & 127;
    WTE[n*128 + k] = f2bf(EW[(size_t)k*128 + n]);
    if (r < 128) sraw[r] = 0.f;
  }
}

// ===== fused per-layer MFMA kernel: 512-thr / 128-row blocks (r17/r20 EXACT) =====
__global__ __launch_bounds__(512, 2) void k_layer(
    float* __restrict__ e,
    const u16* __restrict__ WTC, const u16* __restrict__ WTP,
    const float* __restrict__ Cb, const float* __restrict__ Ax,
    const float* __restrict__ Bx, const float* __restrict__ Vh,
    const float* __restrict__ lnes_g, const float* __restrict__ lneb_g,
    const float* __restrict__ tp_g,
    const float* __restrict__ plos_g, const float* __restrict__ plobl_g,
    const float* __restrict__ plob_g,
    float* __restrict__ aggP) {

  __shared__ __align__(16) u16 Abuf[128*128];   // 32 KB (e, then sv)
  __shared__ __align__(16) u16 Wbuf[128*128];   // 32 KB (WTC, then WTP)

  const int tid = threadIdx.x;
  const int blk0 = blockIdx.x;
  const int blk = ((blk0 & 7) << 7) | (blk0 >> 3);   // XCD swizzle (1024%8==0)
  const int bi  = blk >> 1;          // b*256 + i
  const int b   = bi >> 8;
  const int jh  = blk & 1;           // 128-row half
  const size_t rbase = (size_t)bi*256 + jh*128;

  const int w  = tid >> 6;           // 0..7
  const int l  = tid & 63;
  const int lg = l >> 4;             // 0..3
  const int ln = l & 15;             // 0..15

  {
    const int r = tid >> 2;          // 0..127
    const int p = tid & 3;
    const float* src = e + (rbase + r)*128 + p*32;
    const int r7 = r & 7;
    u16* arow = Abuf + r*128;
#pragma unroll
    for (int q = 0; q < 4; ++q) {
      float4 f0 = *reinterpret_cast<const float4*>(src + q*8);
      float4 f1 = *reinterpret_cast<const float4*>(src + q*8 + 4);
      int pc = (p*4 + q) ^ r7;
      ushort8 h = {f2bf(f0.x),f2bf(f0.y),f2bf(f0.z),f2bf(f0.w),
                   f2bf(f1.x),f2bf(f1.y),f2bf(f1.z),f2bf(f1.w)};
      *reinterpret_cast<ushort8*>(arow + pc*8) = h;
    }
  }
  {
    const int r = tid >> 2;          // 0..127
    const int h = tid & 3;
    const int r7 = r & 7;
    const u16* src = WTC + r*128;
    u16* dst = Wbuf + r*128;
#pragma unroll
    for (int q = 0; q < 4; ++q) {
      int c = h*4 + q;               // 16B chunk index 0..15
      short8 v = *reinterpret_cast<const short8*>(src + c*8);
      *reinterpret_cast<short8*>(dst + ((c ^ r7) << 3)) = v;
    }
  }
  __syncthreads();   // barrier 1

  const int lrow0 = w*16 + lg*4;
  const int jrow0 = jh*128 + lrow0;

  f32x4 acc[8];
#pragma unroll
  for (int nt = 0; nt < 8; ++nt) {
    const int c = nt*16 + ln;
    const float cbax = Cb[c] + Ax[(size_t)bi*128 + c];
#pragma unroll
    for (int rg = 0; rg < 4; ++rg)
      acc[nt][rg] = cbax + Bx[((size_t)b*256 + jrow0 + rg)*128 + c];
  }

  {
    const u16* arow = Abuf + (w*16 + ln)*128;
    const int r7 = ln & 7;
#pragma unroll
    for (int ks = 0; ks < 4; ++ks) {
      short8 a = *reinterpret_cast<const short8*>(arow + (((ks*4 + lg) ^ r7) << 3));
#pragma unroll
      for (int nt = 0; nt < 8; ++nt) {
        short8 bw = *reinterpret_cast<const short8*>(
            Wbuf + (nt*16 + ln)*128 + (((ks*4 + lg) ^ (ln & 7)) << 3));
        acc[nt] = __builtin_amdgcn_mfma_f32_16x16x32_bf16(a, bw, acc[nt], 0, 0, 0);
      }
    }
  }

  float av[8] = {0.f,0.f,0.f,0.f,0.f,0.f,0.f,0.f};
  float tp_[8], ls_[8], lb_[8], ps_[8], pl_[8];
#pragma unroll
  for (int nt = 0; nt < 8; ++nt) {
    const int c = nt*16 + ln;
    tp_[nt] = tp_g[b*128 + c];
    ls_[nt] = lnes_g[c];  lb_[nt] = lneb_g[c];
    ps_[nt] = plos_g[c];  pl_[nt] = plobl_g[c];
  }

#pragma unroll
  for (int rg = 0; rg < 4; ++rg) {
    float ss = 0.f, s2 = 0.f;
#pragma unroll
    for (int nt = 0; nt < 8; ++nt) { float g = acc[nt][rg]; ss += g; s2 += g*g; }
    ss += __shfl_xor(ss, 1);  s2 += __shfl_xor(s2, 1);
    ss += __shfl_xor(ss, 2);  s2 += __shfl_xor(s2, 2);
    ss += __shfl_xor(ss, 4);  s2 += __shfl_xor(s2, 4);
    ss += __shfl_xor(ss, 8);  s2 += __shfl_xor(s2, 8);
    const float mean = ss * (1.f/128.f);
    const float rs = rsqrtf(s2 * (1.f/128.f) - mean*mean + 1e-5f);
    const size_t vrow = ((size_t)b*256 + jrow0 + rg)*128;
    float s3 = 0.f, s4 = 0.f;
#pragma unroll
    for (int nt = 0; nt < 8; ++nt) {
      const float g = acc[nt][rg];
      av[nt] += Vh[vrow + nt*16 + ln] * sigmoidf_(g);
      float tv = fmaxf((g - mean)*rs*ls_[nt] + lb_[nt], 0.f) + tp_[nt];
      acc[nt][rg] = tv;
      s3 += tv;  s4 += tv*tv;
    }
    s3 += __shfl_xor(s3, 1);  s4 += __shfl_xor(s4, 1);
    s3 += __shfl_xor(s3, 2);  s4 += __shfl_xor(s4, 2);
    s3 += __shfl_xor(s3, 4);  s4 += __shfl_xor(s4, 4);
    s3 += __shfl_xor(s3, 8);  s4 += __shfl_xor(s4, 8);
    const float mean2 = s3 * (1.f/128.f);
    const float rs2 = rsqrtf(s4 * (1.f/128.f) - mean2*mean2 + 1e-5f);
    const int rr = lrow0 + rg;
    const int rr7 = rr & 7;
#pragma unroll
    for (int nt = 0; nt < 8; ++nt) {
      float vv = (acc[nt][rg] - mean2)*rs2*ps_[nt] + pl_[nt];
      vv = vv * sigmoidf_(vv);
      const int cc = nt*16 + ln;
      const int pc = (cc >> 3) ^ rr7;
      Abuf[rr*128 + pc*8 + (cc & 7)] = f2bf(vv);
    }
  }

  __syncthreads();
  {
    const int r = tid >> 2;
    const int h = tid & 3;
    const int r7 = r & 7;
    const u16* src = WTP + r*128;
    u16* dst = Wbuf + r*128;
#pragma unroll
    for (int q = 0; q < 4; ++q) {
      int c = h*4 + q;
      short8 v = *reinterpret_cast<const short8*>(src + c*8);
      *reinterpret_cast<short8*>(dst + ((c ^ r7) << 3)) = v;
    }
  }
  __syncthreads();

  f32x4 acc2[8];
#pragma unroll
  for (int nt = 0; nt < 8; ++nt) acc2[nt] = (f32x4)(0.f);
  {
    const u16* arow = Abuf + (w*16 + ln)*128;
    const int r7 = ln & 7;
#pragma unroll
    for (int ks = 0; ks < 4; ++ks) {
      short8 a = *reinterpret_cast<const short8*>(arow + (((ks*4 + lg) ^ r7) << 3));
#pragma unroll
      for (int nt = 0; nt < 8; ++nt) {
        short8 bw = *reinterpret_cast<const short8*>(
            Wbuf + (nt*16 + ln)*128 + (((ks*4 + lg) ^ (ln & 7)) << 3));
        acc2[nt] = __builtin_amdgcn_mfma_f32_16x16x32_bf16(a, bw, acc2[nt], 0, 0, 0);
      }
    }
  }

#pragma unroll
  for (int nt = 0; nt < 8; ++nt) {
    const float pbv = plob_g[nt*16 + ln];
#pragma unroll
    for (int rg = 0; rg < 4; ++rg) {
      float* ep = e + (rbase + lrow0 + rg)*128 + nt*16 + ln;
      *ep = *ep + acc2[nt][rg] + pbv;
    }
  }

#pragma unroll
  for (int nt = 0; nt < 8; ++nt) {
    float v = av[nt];
    v += __shfl_xor(v, 16);
    v += __shfl_xor(v, 32);
    av[nt] = v;
  }
  if (lg == 0) {
#pragma unroll
    for (int nt = 0; nt < 8; ++nt)
      aggP[((size_t)blk*8 + w)*128 + nt*16 + ln] = av[nt];
  }
}

// ===== k_layer_s: identical to k_layer + GN-stats accumulation (layer 3) =====
__global__ __launch_bounds__(512, 2) void k_layer_s(
    float* __restrict__ e,
    const u16* __restrict__ WTC, const u16* __restrict__ WTP,
    const float* __restrict__ Cb, const float* __restrict__ Ax,
    const float* __restrict__ Bx, const float* __restrict__ Vh,
    const float* __restrict__ lnes_g, const float* __restrict__ lneb_g,
    const float* __restrict__ tp_g,
    const float* __restrict__ plos_g, const float* __restrict__ plobl_g,
    const float* __restrict__ plob_g,
    float* __restrict__ aggP, float* __restrict__ sraw) {

  __shared__ __align__(16) u16 Abuf[128*128];
  __shared__ __align__(16) u16 Wbuf[128*128];
  __shared__ float sgrp[64];

  const int tid = threadIdx.x;
  const int blk0 = blockIdx.x;
  const int blk = ((blk0 & 7) << 7) | (blk0 >> 3);
  const int bi  = blk >> 1;
  const int b   = bi >> 8;
  const int jh  = blk & 1;
  const size_t rbase = (size_t)bi*256 + jh*128;

  const int w  = tid >> 6;
  const int l  = tid & 63;
  const int lg = l >> 4;
  const int ln = l & 15;

  {
    const int r = tid >> 2;
    const int p = tid & 3;
    const float* src = e + (rbase + r)*128 + p*32;
    const int r7 = r & 7;
    u16* arow = Abuf + r*128;
#pragma unroll
    for (int q = 0; q < 4; ++q) {
      float4 f0 = *reinterpret_cast<const float4*>(src + q*8);
      float4 f1 = *reinterpret_cast<const float4*>(src + q*8 + 4);
      int pc = (p*4 + q) ^ r7;
      ushort8 h = {f2bf(f0.x),f2bf(f0.y),f2bf(f0.z),f2bf(f0.w),
                   f2bf(f1.x),f2bf(f1.y),f2bf(f1.z),f2bf(f1.w)};
      *reinterpret_cast<ushort8*>(arow + pc*8) = h;
    }
  }
  {
    const int r = tid >> 2;
    const int h = tid & 3;
    const int r7 = r & 7;
    const u16* src = WTC + r*128;
    u16* dst = Wbuf + r*128;
#pragma unroll
    for (int q = 0; q < 4; ++q) {
      int c = h*4 + q;
      short8 v = *reinterpret_cast<const short8*>(src + c*8);
      *reinterpret_cast<short8*>(dst + ((c ^ r7) << 3)) = v;
    }
  }
  if (tid < 64) sgrp[tid] = 0.f;
  __syncthreads();

  const int lrow0 = w*16 + lg*4;
  const int jrow0 = jh*128 + lrow0;

  f32x4 acc[8];
#pragma unroll
  for (int nt = 0; nt < 8; ++nt) {
    const int c = nt*16 + ln;
    const float cbax = Cb[c] + Ax[(size_t)bi*128 + c];
#pragma unroll
    for (int rg = 0; rg < 4; ++rg)
      acc[nt][rg] = cbax + Bx[((size_t)b*256 + jrow0 + rg)*128 + c];
  }

  {
    const u16* arow = Abuf + (w*16 + ln)*128;
    const int r7 = ln & 7;
#pragma unroll
    for (int ks = 0; ks < 4; ++ks) {
      short8 a = *reinterpret_cast<const short8*>(arow + (((ks*4 + lg) ^ r7) << 3));
#pragma unroll
      for (int nt = 0; nt < 8; ++nt) {
        short8 bw = *reinterpret_cast<const short8*>(
            Wbuf + (nt*16 + ln)*128 + (((ks*4 + lg) ^ (ln & 7)) << 3));
        acc[nt] = __builtin_amdgcn_mfma_f32_16x16x32_bf16(a, bw, acc[nt], 0, 0, 0);
      }
    }
  }

  float av[8] = {0.f,0.f,0.f,0.f,0.f,0.f,0.f,0.f};
  float tp_[8], ls_[8], lb_[8], ps_[8], pl_[8];
#pragma unroll
  for (int nt = 0; nt < 8; ++nt) {
    const int c = nt*16 + ln;
    tp_[nt] = tp_g[b*128 + c];
    ls_[nt] = lnes_g[c];  lb_[nt] = lneb_g[c];
    ps_[nt] = plos_g[c];  pl_[nt] = plobl_g[c];
  }

#pragma unroll
  for (int rg = 0; rg < 4; ++rg) {
    float ss = 0.f, s2 = 0.f;
#pragma unroll
    for (int nt = 0; nt < 8; ++nt) { float g = acc[nt][rg]; ss += g; s2 += g*g; }
    ss += __shfl_xor(ss, 1);  s2 += __shfl_xor(s2, 1);
    ss += __shfl_xor(ss, 2);  s2 += __shfl_xor(s2, 2);
    ss += __shfl_xor(ss, 4);  s2 += __shfl_xor(s2, 4);
    ss += __shfl_xor(ss, 8);  s2 += __shfl_xor(s2, 8);
    const float mean = ss * (1.f/128.f);
    const float rs = rsqrtf(s2 * (1.f/128.f) - mean*mean + 1e-5f);
    const size_t vrow = ((size_t)b*256 + jrow0 + rg)*128;
    float s3 = 0.f, s4 = 0.f;
#pragma unroll
    for (int nt = 0; nt < 8; ++nt) {
      const float g = acc[nt][rg];
      av[nt] += Vh[vrow + nt*16 + ln] * sigmoidf_(g);
      float tv = fmaxf((g - mean)*rs*ls_[nt] + lb_[nt], 0.f) + tp_[nt];
      acc[nt][rg] = tv;
      s3 += tv;  s4 += tv*tv;
    }
    s3 += __shfl_xor(s3, 1);  s4 += __shfl_xor(s4, 1);
    s3 += __shfl_xor(s3, 2);  s4 += __shfl_xor(s4, 2);
    s3 += __shfl_xor(s3, 4);  s4 += __shfl_xor(s4, 4);
    s3 += __shfl_xor(s3, 8);  s4 += __shfl_xor(s4, 8);
    const float mean2 = s3 * (1.f/128.f);
    const float rs2 = rsqrtf(s4 * (1.f/128.f) - mean2*mean2 + 1e-5f);
    const int rr = lrow0 + rg;
    const int rr7 = rr & 7;
#pragma unroll
    for (int nt = 0; nt < 8; ++nt) {
      float vv = (acc[nt][rg] - mean2)*rs2*ps_[nt] + pl_[nt];
      vv = vv * sigmoidf_(vv);
      const int cc = nt*16 + ln;
      const int pc = (cc >> 3) ^ rr7;
      Abuf[rr*128 + pc*8 + (cc & 7)] = f2bf(vv);
    }
  }

  __syncthreads();
  {
    const int r = tid >> 2;
    const int h = tid & 3;
    const int r7 = r & 7;
    const u16* src = WTP + r*128;
    u16* dst = Wbuf + r*128;
#pragma unroll
    for (int q = 0; q < 4; ++q) {
      int c = h*4 + q;
      short8 v = *reinterpret_cast<const short8*>(src + c*8);
      *reinterpret_cast<short8*>(dst + ((c ^ r7) << 3)) = v;
    }
  }
  __syncthreads();

  f32x4 acc2[8];
#pragma unroll
  for (int nt = 0; nt < 8; ++nt) acc2[nt] = (f32x4)(0.f);
  {
    const u16* arow = Abuf + (w*16 + ln)*128;
    const int r7 = ln & 7;
#pragma unroll
    for (int ks = 0; ks < 4; ++ks) {
      short8 a = *reinterpret_cast<const short8*>(arow + (((ks*4 + lg) ^ r7) << 3));
#pragma unroll
      for (int nt = 0; nt < 8; ++nt) {
        short8 bw = *reinterpret_cast<const short8*>(
            Wbuf + (nt*16 + ln)*128 + (((ks*4 + lg) ^ (ln & 7)) << 3));
        acc2[nt] = __builtin_amdgcn_mfma_f32_16x16x32_bf16(a, bw, acc2[nt], 0, 0, 0);
      }
    }
  }

#pragma unroll
  for (int nt = 0; nt < 8; ++nt) {
    const float pbv = plob_g[nt*16 + ln];
#pragma unroll
    for (int rg = 0; rg < 4; ++rg) {
      float* ep = e + (rbase + lrow0 + rg)*128 + nt*16 + ln;
      float v = *ep + acc2[nt][rg] + pbv;
      *ep = v;
      acc2[nt][rg] = v;              // keep final value for stats
    }
  }

  // ---- GN stats: group g = nt*4 + (ln>>2) (r16/r21-proven) ----
#pragma unroll
  for (int nt = 0; nt < 8; ++nt) {
    float gs = acc2[nt][0] + acc2[nt][1] + acc2[nt][2] + acc2[nt][3];
    float gq = acc2[nt][0]*acc2[nt][0] + acc2[nt][1]*acc2[nt][1]
             + acc2[nt][2]*acc2[nt][2] + acc2[nt][3]*acc2[nt][3];
    gs += __shfl_xor(gs, 1);  gq += __shfl_xor(gq, 1);
    gs += __shfl_xor(gs, 2);  gq += __shfl_xor(gq, 2);
    gs += __shfl_xor(gs, 16); gq += __shfl_xor(gq, 16);
    gs += __shfl_xor(gs, 32); gq += __shfl_xor(gq, 32);
    if ((l & 51) == 0) {             // ln&3==0 && lg==0
      int g = nt*4 + (ln >> 2);
      atomicAdd(&sgrp[g*2],     gs);
      atomicAdd(&sgrp[g*2 + 1], gq);
    }
  }
  __syncthreads();
  if (tid < 64)
    atomicAdd(&sraw[(size_t)b*64 + tid], sgrp[tid]);

#pragma unroll
  for (int nt = 0; nt < 8; ++nt) {
    float v = av[nt];
    v += __shfl_xor(v, 16);
    v += __shfl_xor(v, 32);
    av[nt] = v;
  }
  if (lg == 0) {
#pragma unroll
    for (int nt = 0; nt < 8; ++nt)
      aggP[((size_t)blk*8 + w)*128 + nt*16 + ln] = av[nt];
  }
}

// ---------------- x update: x += relu(LN(Uh + agg)) (final layer only) --------
__global__ __launch_bounds__(128) void k_xupd(
    const float* __restrict__ aggP, const float* __restrict__ Uh,
    const float* __restrict__ lnh_s, const float* __restrict__ lnh_b,
    float* __restrict__ x) {
  int bi = blockIdx.x, d = threadIdx.x;
  float u = Uh[(size_t)bi*128 + d];
#pragma unroll
  for (int st = 0; st < 16; ++st) u += aggP[((size_t)bi*16 + st)*128 + d];
  float s = u, s2 = u*u;
#pragma unroll
  for (int m = 1; m <= 32; m <<= 1) { s += __shfl_xor(s, m); s2 += __shfl_xor(s2, m); }
  __shared__ float red[4];
  int wid = d >> 6;
  if ((d & 63) == 0) { red[wid] = s; red[2 + wid] = s2; }
  __syncthreads();
  s = red[0] + red[1];  s2 = red[2] + red[3];
  float mean = s * (1.f/128.f);
  float rs = rsqrtf(s2 * (1.f/128.f) - mean*mean + 1e-5f);
  x[(size_t)bi*128 + d] += fmaxf((u - mean)*rs*lnh_s[d] + lnh_b[d], 0.f);
}

// ---- final: out = relu(gn(e)) . conv_W + conv_b; gnfin folded in ----
__global__ __launch_bounds__(256) void k_out(
    const float* __restrict__ e, const float* __restrict__ sraw,
    const float* __restrict__ gn_s, const float* __restrict__ gn_b,
    const float* __restrict__ convW, const float* __restrict__ convb,
    float* __restrict__ out) {
  __shared__ float st[64];           // [g*2]=mean, [g*2+1]=rs for this block's b
  int tid = threadIdx.x;
  size_t b = ((size_t)blockIdx.x*64) >> 16;   // constant per block
  if (tid < 32) {
    const float cnt = (float)(NN*NN*4);
    float S  = sraw[b*64 + tid*2];
    float S2 = sraw[b*64 + tid*2 + 1];
    float mean = S / cnt;
    float var = S2 / cnt - mean*mean;
    st[tid*2]     = mean;
    st[tid*2 + 1] = rsqrtf(var + 1e-5f);
  }
  __syncthreads();
  int row = tid >> 2, part = tid & 3;
  size_t R = (size_t)blockIdx.x*64 + row;
  float acc = 0.f;
  const float4* er = reinterpret_cast<const float4*>(e + R*128 + part*32);
#pragma unroll
  for (int q = 0; q < 8; ++q) {
    float4 f = er[q];
    float fv[4] = {f.x, f.y, f.z, f.w};
#pragma unroll
    for (int lidx = 0; lidx < 4; ++lidx) {
      int c = part*32 + q*4 + lidx;
      int g = c >> 2;
      float mean = st[g*2 + 0];
      float rs   = st[g*2 + 1];
      float t = (fv[lidx] - mean)*rs*gn_s[c] + gn_b[c];
      acc += fmaxf(t, 0.f) * convW[c];
    }
  }
  acc += __shfl_xor(acc, 1);
  acc += __shfl_xor(acc, 2);
  if (part == 0) out[R] = acc + convb[0];
}

extern "C" void kernel_launch(void* const* d_in, const int* in_sizes, int n_in,
                              void* d_out, int out_size, void* d_ws, size_t ws_size,
                              hipStream_t stream) {
  const float* coords  = (const float*)d_in[0];
  const float* adj_t   = (const float*)d_in[1];
  const float* t       = (const float*)d_in[2];
  const float* node_W  = (const float*)d_in[3];
  const float* node_b  = (const float*)d_in[4];
  const float* edge_W  = (const float*)d_in[5];
  const float* edge_b  = (const float*)d_in[6];
  const float* te1_W   = (const float*)d_in[7];
  const float* te1_b   = (const float*)d_in[8];
  const float* te2_W   = (const float*)d_in[9];
  const float* te2_b   = (const float*)d_in[10];
  const float* A_W     = (const float*)d_in[11];
  const float* A_b     = (const float*)d_in[12];
  const float* B_W     = (const float*)d_in[13];
  const float* B_b     = (const float*)d_in[14];
  const float* C_W     = (const float*)d_in[15];
  const float* C_b     = (const float*)d_in[16];
  const float* U_W     = (const float*)d_in[17];
  const float* U_b     = (const float*)d_in[18];
  const float* V_W     = (const float*)d_in[19];
  const float* V_b     = (const float*)d_in[20];
  const float* lnh_s   = (const float*)d_in[21];
  const float* lnh_b   = (const float*)d_in[22];
  const float* lne_s   = (const float*)d_in[23];
  const float* lne_b   = (const float*)d_in[24];
  const float* tl_W    = (const float*)d_in[25];
  const float* tl_b    = (const float*)d_in[26];
  const float* plo_ln_s= (const float*)d_in[27];
  const float* plo_ln_b= (const float*)d_in[28];
  const float* plo_W   = (const float*)d_in[29];
  const float* plo_b   = (const float*)d_in[30];
  const float* gn_s    = (const float*)d_in[31];
  const float* gn_b    = (const float*)d_in[32];
  const float* conv_W  = (const float*)d_in[33];
  const float* conv_b  = (const float*)d_in[34];

  float* ws    = (float*)d_ws;
  float* e     = ws;                        // 16,777,216 floats
  float* x     = e + (size_t)NROWS*128;
  float* Uh    = x + 65536;
  float* Vh    = Uh + 65536;
  float* Ax    = Vh + 65536;
  float* Bx    = Ax + 65536;
  float* tproj = Bx + 65536;                // 1024
  float* sraw  = tproj + 1024;              // 128 (b*64 + g*2 + {0,1})
  float* aggP  = sraw + 128;                // 1024*8*128 = 1,048,576
  u16*   WTC   = (u16*)(aggP + 1048576);    // 4*16384 u16
  u16*   WTP   = WTC + (size_t)LL*16384;
  u16*   WTE   = WTP + (size_t)LL*16384;    // 16384 u16

  k_wprep<<<576, 256, 0, stream>>>(C_W, plo_W, edge_W, WTC, WTP, WTE, sraw);
  k_time<<<1, 512, 0, stream>>>(t, te1_W, te1_b, te2_W, te2_b, tl_W, tl_b, tproj);
  k_node_embed<<<8, 256, 0, stream>>>(coords, node_W, node_b, x);
  k_edge_embed2<<<NROWS/64, 256, 0, stream>>>(adj_t, WTE, edge_b, e);

  for (int i = 0; i < LL; ++i) {
    if (i == 0) {
      k_node4<<<BB*NN, 128, 0, stream>>>(x,
          U_W, U_b, V_W, V_b, A_W, A_b, B_W, B_b,
          Uh, Vh, Ax, Bx);
    } else {
      k_xnode<<<BB*NN, 128, 0, stream>>>(aggP,
          lnh_s + (i-1)*128, lnh_b + (i-1)*128, x,
          U_W + (size_t)i*16384, U_b + i*128,
          V_W + (size_t)i*16384, V_b + i*128,
          A_W + (size_t)i*16384, A_b + i*128,
          B_W + (size_t)i*16384, B_b + i*128,
          Uh, Vh, Ax, Bx);
    }
    if (i < LL-1) {
      k_layer<<<NROWS/128, 512, 0, stream>>>(e,
          WTC + (size_t)i*16384, WTP + (size_t)i*16384,
          C_b + i*128, Ax, Bx, Vh,
          lne_s + i*128, lne_b + i*128,
          tproj + i*BB*128,
          plo_ln_s + i*128, plo_ln_b + i*128, plo_b + i*128,
          aggP);
    } else {
      k_layer_s<<<NROWS/128, 512, 0, stream>>>(e,
          WTC + (size_t)i*16384, WTP + (size_t)i*16384,
          C_b + i*128, Ax, Bx, Vh,
          lne_s + i*128, lne_b + i*128,
          tproj + i*BB*128,
          plo_ln_s + i*128, plo_ln_b + i*128, plo_b + i*128,
          aggP, sraw);
    }
  }
  k_xupd<<<BB*NN, 128, 0, stream>>>(aggP, Uh, lnh_s + 3*128, lnh_b + 3*128, x);

  k_out<<<NROWS/64, 256, 0, stream>>>(e, sraw, gn_s, gn_b, conv_W, conv_b,
                                      (float*)d_out);
}